// Round 1
// baseline (3392.070 us; speedup 1.0000x reference)
//
#include <hip/hip_runtime.h>
#include <math.h>

#define T_SEQ     2048
#define HIDDEN_   2048
#define NUM_HEADS 16
#define NUM_KV    8
#define HEAD_DIM  128
#define Q_SIZE    2048
#define KV_SIZE   1024
#define QKV_N     4096
#define EPS_      1e-6f

// ---------------------------------------------------------------------------
// GEMM: C[M,N] = A[M,K] * B[N,K]^T   (both operands K-contiguous, "NT")
// 64x64 block tile, 256 threads, 4x4 register micro-tile, BK=16.
// ---------------------------------------------------------------------------
__global__ __launch_bounds__(256) void gemm_nt_f32(
    const float* __restrict__ A, const float* __restrict__ B,
    float* __restrict__ C, int M, int N, int K)
{
    __shared__ float As[16][68];   // [k][m], pad to 68 (272B rows: 16B aligned, 2-way banks)
    __shared__ float Bs[16][68];   // [k][n]
    const int tid = threadIdx.x;
    const int bm = blockIdx.y * 64;
    const int bn = blockIdx.x * 64;
    const int tx = tid & 15;       // n
    const int ty = tid >> 4;       // m
    const int lr = tid >> 2;       // 0..63 row within tile
    const int lk = (tid & 3) << 2; // 0,4,8,12 k offset
    const float* aptr = A + (size_t)(bm + lr) * K + lk;
    const float* bptr = B + (size_t)(bn + lr) * K + lk;
    float acc[4][4] = {};
    for (int k0 = 0; k0 < K; k0 += 16) {
        float4 av = *(const float4*)(aptr + k0);
        float4 bv = *(const float4*)(bptr + k0);
        __syncthreads();
        As[lk+0][lr]=av.x; As[lk+1][lr]=av.y; As[lk+2][lr]=av.z; As[lk+3][lr]=av.w;
        Bs[lk+0][lr]=bv.x; Bs[lk+1][lr]=bv.y; Bs[lk+2][lr]=bv.z; Bs[lk+3][lr]=bv.w;
        __syncthreads();
        #pragma unroll
        for (int kk = 0; kk < 16; ++kk) {
            float4 a4 = *(const float4*)&As[kk][ty << 2];
            float4 b4 = *(const float4*)&Bs[kk][tx << 2];
            float ar[4] = {a4.x, a4.y, a4.z, a4.w};
            float br[4] = {b4.x, b4.y, b4.z, b4.w};
            #pragma unroll
            for (int i2 = 0; i2 < 4; ++i2)
                #pragma unroll
                for (int j2 = 0; j2 < 4; ++j2)
                    acc[i2][j2] = fmaf(ar[i2], br[j2], acc[i2][j2]);
        }
    }
    #pragma unroll
    for (int i2 = 0; i2 < 4; ++i2) {
        float4 o = make_float4(acc[i2][0], acc[i2][1], acc[i2][2], acc[i2][3]);
        *(float4*)(C + (size_t)(bm + (ty<<2) + i2) * N + bn + (tx<<2)) = o;
    }
}

// ---------------------------------------------------------------------------
// Fused RMSNorm + RoPE, in-place on the qkv buffer.
// grid = (T, 24): 16 q-heads then 8 k-heads.  block = 128 (one lane per dim).
// ---------------------------------------------------------------------------
__global__ __launch_bounds__(128) void normrope(
    float* __restrict__ qkv, const int* __restrict__ positions,
    const float* __restrict__ qw, const float* __restrict__ kw)
{
    const int i = blockIdx.x;
    const int h = blockIdx.y;
    const int t = threadIdx.x;
    float* ptr;
    const float* w;
    if (h < NUM_HEADS) { ptr = qkv + (size_t)i * QKV_N + h * HEAD_DIM; w = qw; }
    else { ptr = qkv + (size_t)i * QKV_N + Q_SIZE + (h - NUM_HEADS) * HEAD_DIM; w = kw; }

    float x = ptr[t];
    float v = x * x;
    #pragma unroll
    for (int off = 32; off; off >>= 1) v += __shfl_xor(v, off, 64);
    __shared__ float sh[2];
    __shared__ float xn[HEAD_DIM];
    if ((t & 63) == 0) sh[t >> 6] = v;
    __syncthreads();
    const float sumsq = sh[0] + sh[1];
    const float inv = rsqrtf(sumsq * (1.0f / HEAD_DIM) + EPS_);
    xn[t] = x * inv * w[t];
    __syncthreads();

    const int d = t & 63;
    // inv_freq = theta^(-d/64) = 2^(-d * log2(1e4)/64)
    const float fr = (float)positions[i] * exp2f(-(float)d * (13.287712379549449f / 64.0f));
    float s, c;
    sincosf(fr, &s, &c);
    const float x1 = xn[d], x2 = xn[d + 64];
    ptr[t] = (t < 64) ? (x1 * c - x2 * s) : (x2 * c + x1 * s);
}

// ---------------------------------------------------------------------------
// Causal attention: one block per (token i, q-head h). 128 threads.
// Scores for all j<=i staged in LDS; two-pass softmax; ctx accumulation with
// one lane per head-dim.
// ---------------------------------------------------------------------------
__global__ __launch_bounds__(128) void attn(
    const float* __restrict__ qkv, float* __restrict__ ctx)
{
    const int i = blockIdx.x;
    const int h = blockIdx.y;
    const int kv = h >> 1;           // G = 2
    const int t = threadIdx.x;
    __shared__ float qs[HEAD_DIM];
    __shared__ float sc[T_SEQ];
    __shared__ float red[2];

    const float* qp = qkv + (size_t)i * QKV_N + h * HEAD_DIM;
    qs[t] = qp[t] * 0.08838834764831845f;   // fold 1/sqrt(128) into q
    __syncthreads();

    const int L = i + 1;
    const float* kbase = qkv + Q_SIZE + (size_t)kv * HEAD_DIM;
    float lmax = -1e30f;
    for (int j = t; j < L; j += 128) {
        const float* kp = kbase + (size_t)j * QKV_N;
        float s = 0.f;
        #pragma unroll
        for (int d4 = 0; d4 < HEAD_DIM; d4 += 4) {
            float4 kw4 = *(const float4*)(kp + d4);
            float4 q4  = *(const float4*)(qs + d4);
            s = fmaf(q4.x, kw4.x, s); s = fmaf(q4.y, kw4.y, s);
            s = fmaf(q4.z, kw4.z, s); s = fmaf(q4.w, kw4.w, s);
        }
        sc[j] = s;
        lmax = fmaxf(lmax, s);
    }
    #pragma unroll
    for (int off = 32; off; off >>= 1) lmax = fmaxf(lmax, __shfl_xor(lmax, off, 64));
    if ((t & 63) == 0) red[t >> 6] = lmax;
    __syncthreads();
    const float m = fmaxf(red[0], red[1]);

    float lsum = 0.f;
    for (int j = t; j < L; j += 128) {
        float e = __expf(sc[j] - m);
        sc[j] = e;
        lsum += e;
    }
    #pragma unroll
    for (int off = 32; off; off >>= 1) lsum += __shfl_xor(lsum, off, 64);
    __syncthreads();                       // red reads done; sc writes visible after next sync
    if ((t & 63) == 0) red[t >> 6] = lsum;
    __syncthreads();
    const float rden = 1.0f / (red[0] + red[1]);

    const float* vbase = qkv + Q_SIZE + KV_SIZE + (size_t)kv * HEAD_DIM + t;
    float acc = 0.f;
    #pragma unroll 4
    for (int j = 0; j < L; ++j)
        acc = fmaf(sc[j], vbase[(size_t)j * QKV_N], acc);
    ctx[(size_t)i * Q_SIZE + h * HEAD_DIM + t] = acc * rden;
}

// ---------------------------------------------------------------------------
extern "C" void kernel_launch(void* const* d_in, const int* in_sizes, int n_in,
                              void* d_out, int out_size, void* d_ws, size_t ws_size,
                              hipStream_t stream)
{
    const int*   positions = (const int*)d_in[0];
    const float* hidden    = (const float*)d_in[1];
    const float* qkv_w     = (const float*)d_in[2];
    const float* q_norm_w  = (const float*)d_in[3];
    const float* k_norm_w  = (const float*)d_in[4];
    const float* o_w       = (const float*)d_in[5];
    float* out = (float*)d_out;

    float* qkv = (float*)d_ws;                       // T x 4096
    float* ctx = qkv + (size_t)T_SEQ * QKV_N;        // T x 2048

    // qkv = hidden @ qkv_w^T
    gemm_nt_f32<<<dim3(QKV_N / 64, T_SEQ / 64), 256, 0, stream>>>(
        hidden, qkv_w, qkv, T_SEQ, QKV_N, HIDDEN_);
    // RMSNorm + RoPE on q and k heads (in place)
    normrope<<<dim3(T_SEQ, NUM_HEADS + NUM_KV), 128, 0, stream>>>(
        qkv, positions, q_norm_w, k_norm_w);
    // causal attention -> ctx
    attn<<<dim3(T_SEQ, NUM_HEADS), 128, 0, stream>>>(qkv, ctx);
    // out = ctx @ o_w^T
    gemm_nt_f32<<<dim3(Q_SIZE / 64, T_SEQ / 64), 256, 0, stream>>>(
        ctx, o_w, out, T_SEQ, Q_SIZE, HIDDEN_);
}

// Round 2
// 969.124 us; speedup vs baseline: 3.5001x; 3.5001x over previous
//
#include <hip/hip_runtime.h>
#include <math.h>

#define T_SEQ     2048
#define HIDDEN_   2048
#define NUM_HEADS 16
#define NUM_KV    8
#define HEAD_DIM  128
#define Q_SIZE    2048
#define KV_SIZE   1024
#define QKV_N     4096
#define EPS_      1e-6f

typedef __attribute__((ext_vector_type(8))) short short8;
typedef __attribute__((ext_vector_type(4))) float floatx4;

__device__ __forceinline__ unsigned short f2bf(float f) {
    unsigned int u = __float_as_uint(f);
    u += 0x7fffu + ((u >> 16) & 1u);     // RNE
    return (unsigned short)(u >> 16);
}

// ---------------------------------------------------------------------------
// GEMM: C[M,N] = A[M,K] * B[N,K]^T  (fp32, 64x64 tile) — unchanged from R1.
// ---------------------------------------------------------------------------
__global__ __launch_bounds__(256) void gemm_nt_f32(
    const float* __restrict__ A, const float* __restrict__ B,
    float* __restrict__ C, int M, int N, int K)
{
    __shared__ float As[16][68];
    __shared__ float Bs[16][68];
    const int tid = threadIdx.x;
    const int bm = blockIdx.y * 64;
    const int bn = blockIdx.x * 64;
    const int tx = tid & 15;
    const int ty = tid >> 4;
    const int lr = tid >> 2;
    const int lk = (tid & 3) << 2;
    const float* aptr = A + (size_t)(bm + lr) * K + lk;
    const float* bptr = B + (size_t)(bn + lr) * K + lk;
    float acc[4][4] = {};
    for (int k0 = 0; k0 < K; k0 += 16) {
        float4 av = *(const float4*)(aptr + k0);
        float4 bv = *(const float4*)(bptr + k0);
        __syncthreads();
        As[lk+0][lr]=av.x; As[lk+1][lr]=av.y; As[lk+2][lr]=av.z; As[lk+3][lr]=av.w;
        Bs[lk+0][lr]=bv.x; Bs[lk+1][lr]=bv.y; Bs[lk+2][lr]=bv.z; Bs[lk+3][lr]=bv.w;
        __syncthreads();
        #pragma unroll
        for (int kk = 0; kk < 16; ++kk) {
            float4 a4 = *(const float4*)&As[kk][ty << 2];
            float4 b4 = *(const float4*)&Bs[kk][tx << 2];
            float ar[4] = {a4.x, a4.y, a4.z, a4.w};
            float br[4] = {b4.x, b4.y, b4.z, b4.w};
            #pragma unroll
            for (int i2 = 0; i2 < 4; ++i2)
                #pragma unroll
                for (int j2 = 0; j2 < 4; ++j2)
                    acc[i2][j2] = fmaf(ar[i2], br[j2], acc[i2][j2]);
        }
    }
    #pragma unroll
    for (int i2 = 0; i2 < 4; ++i2) {
        float4 o = make_float4(acc[i2][0], acc[i2][1], acc[i2][2], acc[i2][3]);
        *(float4*)(C + (size_t)(bm + (ty<<2) + i2) * N + bn + (tx<<2)) = o;
    }
}

// ---------------------------------------------------------------------------
// Fused RMSNorm + RoPE. q heads: in-place fp32. k heads: write bf16 Kb[kv][T][128].
// grid = (T, 24), block = 128.
// ---------------------------------------------------------------------------
__global__ __launch_bounds__(128) void normrope(
    float* __restrict__ qkv, const int* __restrict__ positions,
    const float* __restrict__ qw, const float* __restrict__ kw,
    unsigned short* __restrict__ Kb)
{
    const int i = blockIdx.x;
    const int h = blockIdx.y;
    const int t = threadIdx.x;
    float* ptr;
    const float* w;
    if (h < NUM_HEADS) { ptr = qkv + (size_t)i * QKV_N + h * HEAD_DIM; w = qw; }
    else { ptr = qkv + (size_t)i * QKV_N + Q_SIZE + (h - NUM_HEADS) * HEAD_DIM; w = kw; }

    float x = ptr[t];
    float v = x * x;
    #pragma unroll
    for (int off = 32; off; off >>= 1) v += __shfl_xor(v, off, 64);
    __shared__ float sh[2];
    __shared__ float xn[HEAD_DIM];
    if ((t & 63) == 0) sh[t >> 6] = v;
    __syncthreads();
    const float sumsq = sh[0] + sh[1];
    const float inv = rsqrtf(sumsq * (1.0f / HEAD_DIM) + EPS_);
    xn[t] = x * inv * w[t];
    __syncthreads();

    const int d = t & 63;
    const float fr = (float)positions[i] * exp2f(-(float)d * (13.287712379549449f / 64.0f));
    float s, c;
    sincosf(fr, &s, &c);
    const float x1 = xn[d], x2 = xn[d + 64];
    const float val = (t < 64) ? (x1 * c - x2 * s) : (x2 * c + x1 * s);
    if (h < NUM_HEADS) ptr[t] = val;
    else Kb[((size_t)(h - NUM_HEADS) * T_SEQ + i) * HEAD_DIM + t] = f2bf(val);
}

// ---------------------------------------------------------------------------
// V: fp32 [T][kv*128] slice of qkv  ->  bf16 transposed Vt[kv][128][T].
// grid = (T/64, 8), block = 256. LDS transpose tile 64x128.
// ---------------------------------------------------------------------------
__global__ __launch_bounds__(256) void convert_v(
    const float* __restrict__ qkv, unsigned short* __restrict__ Vt)
{
    const int kv = blockIdx.y;
    const int t0 = blockIdx.x * 64;
    const int tid = threadIdx.x;
    __shared__ unsigned short L[64][132];
    #pragma unroll
    for (int it = 0; it < 8; ++it) {
        int idx = tid + it * 256;      // 0..2047 float4 chunks
        int tl = idx >> 5;             // token 0..63
        int c4 = idx & 31;             // float4 col chunk
        float4 v = *(const float4*)(qkv + (size_t)(t0 + tl) * QKV_N
                                    + Q_SIZE + KV_SIZE + kv * HEAD_DIM + c4 * 4);
        ushort4 o;
        o.x = f2bf(v.x); o.y = f2bf(v.y); o.z = f2bf(v.z); o.w = f2bf(v.w);
        *(ushort4*)&L[tl][c4 * 4] = o;
    }
    __syncthreads();
    const int c = tid >> 1;
    const int half = tid & 1;
    unsigned short tmp[32] __attribute__((aligned(16)));
    #pragma unroll
    for (int s = 0; s < 32; ++s) tmp[s] = L[half * 32 + s][c];
    unsigned short* dst = Vt + ((size_t)kv * HEAD_DIM + c) * T_SEQ + t0 + half * 32;
    #pragma unroll
    for (int q = 0; q < 4; ++q)
        *(uint4*)(dst + q * 8) = *(const uint4*)(tmp + q * 8);
}

// ---------------------------------------------------------------------------
// Flash attention, bf16 MFMA 16x16x32.
// Block = (q-head h, 64-query tile), 256 threads = 4 waves x 16 q-rows.
// K-tile (32x128) + Vt-tile (128x32) in LDS, shared by waves; P per-wave in LDS.
// ---------------------------------------------------------------------------
#define BQ 64
#define BK 32

__global__ __launch_bounds__(256) void attn_mfma(
    const float* __restrict__ qkv, const unsigned short* __restrict__ Kb,
    const unsigned short* __restrict__ Vt, float* __restrict__ ctx)
{
    const int h = blockIdx.y;
    // interleave light/heavy q-tiles so CU loads balance
    const int bx = blockIdx.x;
    const int qt = (bx & 1) ? (T_SEQ / BQ - 1 - (bx >> 1)) : (bx >> 1);
    const int q0 = qt * BQ;
    const int kv = h >> 1;
    const int tid = threadIdx.x;
    const int w = tid >> 6;
    const int lane = tid & 63;
    const int col = lane & 15;
    const int quad = lane >> 4;

    __shared__ unsigned short Ks[BK][136];    // [token][d]   row 272B
    __shared__ unsigned short Vs[HEAD_DIM][40]; // [d][token] row 80B
    __shared__ unsigned short Ps[4][16][40];  // per-wave P [row][token] row 80B

    // Q A-fragments: rows m = col (lane&15), k = quad*8+j, 4 chunks of K=32
    short8 qf[4];
    {
        const float* qp = qkv + (size_t)(q0 + w * 16 + col) * QKV_N + h * HEAD_DIM;
        #pragma unroll
        for (int c = 0; c < 4; ++c) {
            const float* p = qp + c * 32 + quad * 8;
            float4 a = *(const float4*)p;
            float4 b = *(const float4*)(p + 4);
            const float sc = 0.08838834764831845f;   // 1/sqrt(128)
            qf[c][0] = (short)f2bf(a.x * sc); qf[c][1] = (short)f2bf(a.y * sc);
            qf[c][2] = (short)f2bf(a.z * sc); qf[c][3] = (short)f2bf(a.w * sc);
            qf[c][4] = (short)f2bf(b.x * sc); qf[c][5] = (short)f2bf(b.y * sc);
            qf[c][6] = (short)f2bf(b.z * sc); qf[c][7] = (short)f2bf(b.w * sc);
        }
    }

    floatx4 Ob[8];
    #pragma unroll
    for (int cb = 0; cb < 8; ++cb) Ob[cb] = (floatx4){0.f, 0.f, 0.f, 0.f};
    float m_i[4], l_i[4];
    #pragma unroll
    for (int r = 0; r < 4; ++r) { m_i[r] = -1e30f; l_i[r] = 0.f; }

    const int wave_qmax = q0 + w * 16 + 15;

    for (int t0 = 0; t0 < q0 + BQ; t0 += BK) {
        __syncthreads();
        // stage K tile: 32 tokens x 128 d bf16 (8 KB), 16B per thread x2
        #pragma unroll
        for (int it = 0; it < 2; ++it) {
            int idx = tid + it * 256;
            int r = idx >> 4;
            int o = (idx & 15) << 3;
            uint4 d = *(const uint4*)(Kb + ((size_t)kv * T_SEQ + t0 + r) * HEAD_DIM + o);
            *(uint4*)&Ks[r][o] = d;
        }
        // stage Vt tile: 128 d x 32 tokens bf16 (8 KB)
        #pragma unroll
        for (int it = 0; it < 2; ++it) {
            int idx = tid + it * 256;
            int r = idx >> 2;
            int o = (idx & 3) << 3;
            uint4 d = *(const uint4*)(Vt + ((size_t)kv * HEAD_DIM + r) * T_SEQ + t0 + o);
            *(uint4*)&Vs[r][o] = d;
        }
        __syncthreads();
        if (t0 > wave_qmax) continue;   // wave-uniform: fully masked tile

        // S = Q K^T : two 16-col blocks
        floatx4 S[2];
        #pragma unroll
        for (int cb = 0; cb < 2; ++cb) {
            floatx4 acc = (floatx4){0.f, 0.f, 0.f, 0.f};
            #pragma unroll
            for (int c = 0; c < 4; ++c) {
                short8 kf = *(const short8*)&Ks[cb * 16 + col][c * 32 + quad * 8];
                acc = __builtin_amdgcn_mfma_f32_16x16x32_bf16(qf[c], kf, acc, 0, 0, 0);
            }
            S[cb] = acc;
        }

        // online softmax; lane owns rows quad*4+r, cols cb*16+col
        const int qr_base = q0 + w * 16 + quad * 4;
        #pragma unroll
        for (int r = 0; r < 4; ++r) {
            const int qr = qr_base + r;
            #pragma unroll
            for (int cb = 0; cb < 2; ++cb) {
                int kt = t0 + cb * 16 + col;
                if (kt > qr) S[cb][r] = -1e30f;
            }
            float mx = fmaxf(S[0][r], S[1][r]);
            #pragma unroll
            for (int off = 1; off < 16; off <<= 1)
                mx = fmaxf(mx, __shfl_xor(mx, off, 64));
            const float mnew = fmaxf(m_i[r], mx);
            const float alpha = __expf(m_i[r] - mnew);
            m_i[r] = mnew;
            float rsum = 0.f;
            #pragma unroll
            for (int cb = 0; cb < 2; ++cb) {
                float p = __expf(S[cb][r] - mnew);
                unsigned short pb = f2bf(p);
                Ps[w][quad * 4 + r][cb * 16 + col] = pb;
                unsigned int pu = (unsigned int)pb << 16;
                rsum += __uint_as_float(pu);
            }
            #pragma unroll
            for (int off = 1; off < 16; off <<= 1)
                rsum += __shfl_xor(rsum, off, 64);
            l_i[r] = l_i[r] * alpha + rsum;
            #pragma unroll
            for (int cb = 0; cb < 8; ++cb) Ob[cb][r] *= alpha;
        }

        // PV: P (16xBK) A-frag from LDS; Vt B-frag; same-wave LDS ops are in-order
        short8 pf = *(const short8*)&Ps[w][col][quad * 8];
        #pragma unroll
        for (int cb = 0; cb < 8; ++cb) {
            short8 vf = *(const short8*)&Vs[cb * 16 + col][quad * 8];
            Ob[cb] = __builtin_amdgcn_mfma_f32_16x16x32_bf16(pf, vf, Ob[cb], 0, 0, 0);
        }
    }

    // epilogue: O /= l, write ctx fp32
    #pragma unroll
    for (int cb = 0; cb < 8; ++cb) {
        #pragma unroll
        for (int r = 0; r < 4; ++r) {
            int qr = q0 + w * 16 + quad * 4 + r;
            ctx[(size_t)qr * Q_SIZE + h * HEAD_DIM + cb * 16 + col] = Ob[cb][r] / l_i[r];
        }
    }
}

// ---------------------------------------------------------------------------
extern "C" void kernel_launch(void* const* d_in, const int* in_sizes, int n_in,
                              void* d_out, int out_size, void* d_ws, size_t ws_size,
                              hipStream_t stream)
{
    const int*   positions = (const int*)d_in[0];
    const float* hidden    = (const float*)d_in[1];
    const float* qkv_w     = (const float*)d_in[2];
    const float* q_norm_w  = (const float*)d_in[3];
    const float* k_norm_w  = (const float*)d_in[4];
    const float* o_w       = (const float*)d_in[5];
    float* out = (float*)d_out;

    char* ws = (char*)d_ws;
    float* qkv          = (float*)ws;                                   // 32 MB
    float* ctx          = (float*)(ws + (size_t)32 * 1024 * 1024);      // 16 MB
    unsigned short* Kb  = (unsigned short*)(ws + (size_t)48 * 1024 * 1024); // 4 MB
    unsigned short* Vt  = (unsigned short*)(ws + (size_t)52 * 1024 * 1024); // 4 MB

    gemm_nt_f32<<<dim3(QKV_N / 64, T_SEQ / 64), 256, 0, stream>>>(
        hidden, qkv_w, qkv, T_SEQ, QKV_N, HIDDEN_);
    normrope<<<dim3(T_SEQ, NUM_HEADS + NUM_KV), 128, 0, stream>>>(
        qkv, positions, q_norm_w, k_norm_w, Kb);
    convert_v<<<dim3(T_SEQ / 64, NUM_KV), 256, 0, stream>>>(qkv, Vt);
    attn_mfma<<<dim3(T_SEQ / BQ, NUM_HEADS), 256, 0, stream>>>(qkv, Kb, Vt, ctx);
    gemm_nt_f32<<<dim3(Q_SIZE / 64, T_SEQ / 64), 256, 0, stream>>>(
        ctx, o_w, out, T_SEQ, Q_SIZE, HIDDEN_);
}

// Round 3
// 394.597 us; speedup vs baseline: 8.5963x; 2.4560x over previous
//
#include <hip/hip_runtime.h>
#include <math.h>

#define T_SEQ     2048
#define HIDDEN_   2048
#define NUM_HEADS 16
#define NUM_KV    8
#define HEAD_DIM  128
#define Q_SIZE    2048
#define KV_SIZE   1024
#define QKV_N     4096
#define EPS_      1e-6f

typedef __attribute__((ext_vector_type(8))) short short8;
typedef __attribute__((ext_vector_type(4))) float floatx4;

__device__ __forceinline__ unsigned short f2bf(float f) {
    unsigned int u = __float_as_uint(f);
    u += 0x7fffu + ((u >> 16) & 1u);     // RNE
    return (unsigned short)(u >> 16);
}

__device__ __forceinline__ void stage16(const unsigned short* g, unsigned short* lds_base) {
    __builtin_amdgcn_global_load_lds(
        (const __attribute__((address_space(1))) unsigned int*)g,
        (__attribute__((address_space(3))) unsigned int*)lds_base, 16, 0, 0);
}

// ---------------------------------------------------------------------------
// fp32 -> bf16 bulk convert (n4 = element count / 4)
// ---------------------------------------------------------------------------
__global__ __launch_bounds__(256) void f32_to_bf16(
    const float* __restrict__ in, unsigned short* __restrict__ out, int n4)
{
    int i = blockIdx.x * 256 + threadIdx.x;
    if (i < n4) {
        float4 v = ((const float4*)in)[i];
        ushort4 o;
        o.x = f2bf(v.x); o.y = f2bf(v.y); o.z = f2bf(v.z); o.w = f2bf(v.w);
        ((ushort4*)out)[i] = o;
    }
}

// ---------------------------------------------------------------------------
// bf16 MFMA GEMM: C[M,N] fp32 = A[M,K]bf16 * B[N,K]bf16^T  (NT)
// 128x128 tile, 256 thr = 4 waves, each wave 64x64 = 4x4 MFMA 16x16x32 tiles.
// K staged via global_load_lds(16B); XOR source-swizzle for conflict-free
// ds_read_b128 (phys_chunk = chunk ^ ((row>>1)&3)).
// ---------------------------------------------------------------------------
__global__ __launch_bounds__(256) void gemm_nt_bf16(
    const unsigned short* __restrict__ A, const unsigned short* __restrict__ B,
    float* __restrict__ C, int M, int N, int K)
{
    __shared__ unsigned short As[128 * 32];   // 8 KB, slot-swizzled
    __shared__ unsigned short Bs[128 * 32];   // 8 KB
    const int tid  = threadIdx.x;
    const int w    = tid >> 6;
    const int lane = tid & 63;
    const int col  = lane & 15;
    const int quad = lane >> 4;
    const int bm = blockIdx.y * 128;
    const int bn = blockIdx.x * 128;
    const int wm = (w & 1) * 64;
    const int wn = (w >> 1) * 64;

    floatx4 acc[4][4];
    #pragma unroll
    for (int i = 0; i < 4; ++i)
        #pragma unroll
        for (int j = 0; j < 4; ++j)
            acc[i][j] = (floatx4){0.f, 0.f, 0.f, 0.f};

    // per-lane staging source coords (slot s = cc*256 + tid)
    int s_r[2], s_lc[2];
    #pragma unroll
    for (int cc = 0; cc < 2; ++cc) {
        int s = cc * 256 + tid;
        int r = s >> 2, pc = s & 3;
        s_r[cc] = r;
        s_lc[cc] = pc ^ ((r >> 1) & 3);
    }

    for (int k0 = 0; k0 < K; k0 += 32) {
        __syncthreads();
        #pragma unroll
        for (int cc = 0; cc < 2; ++cc) {
            unsigned short* ldsA = &As[(cc * 256 + w * 64) * 8];
            unsigned short* ldsB = &Bs[(cc * 256 + w * 64) * 8];
            stage16(A + (size_t)(bm + s_r[cc]) * K + k0 + s_lc[cc] * 8, ldsA);
            stage16(B + (size_t)(bn + s_r[cc]) * K + k0 + s_lc[cc] * 8, ldsB);
        }
        __syncthreads();

        short8 af[4], bf[4];
        #pragma unroll
        for (int i = 0; i < 4; ++i) {
            int r = wm + i * 16 + col;
            int pc = quad ^ ((r >> 1) & 3);
            af[i] = *(const short8*)&As[r * 32 + pc * 8];
        }
        #pragma unroll
        for (int j = 0; j < 4; ++j) {
            int r = wn + j * 16 + col;
            int pc = quad ^ ((r >> 1) & 3);
            bf[j] = *(const short8*)&Bs[r * 32 + pc * 8];
        }
        #pragma unroll
        for (int i = 0; i < 4; ++i)
            #pragma unroll
            for (int j = 0; j < 4; ++j)
                acc[i][j] = __builtin_amdgcn_mfma_f32_16x16x32_bf16(af[i], bf[j], acc[i][j], 0, 0, 0);
    }

    #pragma unroll
    for (int i = 0; i < 4; ++i)
        #pragma unroll
        for (int j = 0; j < 4; ++j)
            #pragma unroll
            for (int rr = 0; rr < 4; ++rr) {
                int row = bm + wm + i * 16 + quad * 4 + rr;
                int cc2 = bn + wn + j * 16 + col;
                C[(size_t)row * N + cc2] = acc[i][j][rr];
            }
}

// ---------------------------------------------------------------------------
// Fused RMSNorm + RoPE. q heads: in-place fp32. k heads: bf16 Kb[kv][T][128].
// ---------------------------------------------------------------------------
__global__ __launch_bounds__(128) void normrope(
    float* __restrict__ qkv, const int* __restrict__ positions,
    const float* __restrict__ qw, const float* __restrict__ kw,
    unsigned short* __restrict__ Kb)
{
    const int i = blockIdx.x;
    const int h = blockIdx.y;
    const int t = threadIdx.x;
    float* ptr;
    const float* w;
    if (h < NUM_HEADS) { ptr = qkv + (size_t)i * QKV_N + h * HEAD_DIM; w = qw; }
    else { ptr = qkv + (size_t)i * QKV_N + Q_SIZE + (h - NUM_HEADS) * HEAD_DIM; w = kw; }

    float x = ptr[t];
    float v = x * x;
    #pragma unroll
    for (int off = 32; off; off >>= 1) v += __shfl_xor(v, off, 64);
    __shared__ float sh[2];
    __shared__ float xn[HEAD_DIM];
    if ((t & 63) == 0) sh[t >> 6] = v;
    __syncthreads();
    const float sumsq = sh[0] + sh[1];
    const float inv = rsqrtf(sumsq * (1.0f / HEAD_DIM) + EPS_);
    xn[t] = x * inv * w[t];
    __syncthreads();

    const int d = t & 63;
    const float fr = (float)positions[i] * exp2f(-(float)d * (13.287712379549449f / 64.0f));
    float s, c;
    sincosf(fr, &s, &c);
    const float x1 = xn[d], x2 = xn[d + 64];
    const float val = (t < 64) ? (x1 * c - x2 * s) : (x2 * c + x1 * s);
    if (h < NUM_HEADS) ptr[t] = val;
    else Kb[((size_t)(h - NUM_HEADS) * T_SEQ + i) * HEAD_DIM + t] = f2bf(val);
}

// ---------------------------------------------------------------------------
// V: fp32 [T][kv*128] slice of qkv -> bf16 transposed Vt[kv][128][T].
// ---------------------------------------------------------------------------
__global__ __launch_bounds__(256) void convert_v(
    const float* __restrict__ qkv, unsigned short* __restrict__ Vt)
{
    const int kv = blockIdx.y;
    const int t0 = blockIdx.x * 64;
    const int tid = threadIdx.x;
    __shared__ unsigned short L[64][132];
    #pragma unroll
    for (int it = 0; it < 8; ++it) {
        int idx = tid + it * 256;
        int tl = idx >> 5;
        int c4 = idx & 31;
        float4 v = *(const float4*)(qkv + (size_t)(t0 + tl) * QKV_N
                                    + Q_SIZE + KV_SIZE + kv * HEAD_DIM + c4 * 4);
        ushort4 o;
        o.x = f2bf(v.x); o.y = f2bf(v.y); o.z = f2bf(v.z); o.w = f2bf(v.w);
        *(ushort4*)&L[tl][c4 * 4] = o;
    }
    __syncthreads();
    const int c = tid >> 1;
    const int half = tid & 1;
    unsigned short tmp[32] __attribute__((aligned(16)));
    #pragma unroll
    for (int s = 0; s < 32; ++s) tmp[s] = L[half * 32 + s][c];
    unsigned short* dst = Vt + ((size_t)kv * HEAD_DIM + c) * T_SEQ + t0 + half * 32;
    #pragma unroll
    for (int q = 0; q < 4; ++q)
        *(uint4*)(dst + q * 8) = *(const uint4*)(tmp + q * 8);
}

// ---------------------------------------------------------------------------
// Flash attention, bf16 MFMA 16x16x32. Writes ctx as bf16.
// ---------------------------------------------------------------------------
#define BQ 64
#define BK 32

__global__ __launch_bounds__(256) void attn_mfma(
    const float* __restrict__ qkv, const unsigned short* __restrict__ Kb,
    const unsigned short* __restrict__ Vt, unsigned short* __restrict__ ctxb)
{
    const int h = blockIdx.y;
    const int bx = blockIdx.x;
    const int qt = (bx & 1) ? (T_SEQ / BQ - 1 - (bx >> 1)) : (bx >> 1);
    const int q0 = qt * BQ;
    const int kv = h >> 1;
    const int tid = threadIdx.x;
    const int w = tid >> 6;
    const int lane = tid & 63;
    const int col = lane & 15;
    const int quad = lane >> 4;

    __shared__ unsigned short Ks[BK][136];
    __shared__ unsigned short Vs[HEAD_DIM][40];
    __shared__ unsigned short Ps[4][16][40];

    short8 qf[4];
    {
        const float* qp = qkv + (size_t)(q0 + w * 16 + col) * QKV_N + h * HEAD_DIM;
        #pragma unroll
        for (int c = 0; c < 4; ++c) {
            const float* p = qp + c * 32 + quad * 8;
            float4 a = *(const float4*)p;
            float4 b = *(const float4*)(p + 4);
            const float sc = 0.08838834764831845f;
            qf[c][0] = (short)f2bf(a.x * sc); qf[c][1] = (short)f2bf(a.y * sc);
            qf[c][2] = (short)f2bf(a.z * sc); qf[c][3] = (short)f2bf(a.w * sc);
            qf[c][4] = (short)f2bf(b.x * sc); qf[c][5] = (short)f2bf(b.y * sc);
            qf[c][6] = (short)f2bf(b.z * sc); qf[c][7] = (short)f2bf(b.w * sc);
        }
    }

    floatx4 Ob[8];
    #pragma unroll
    for (int cb = 0; cb < 8; ++cb) Ob[cb] = (floatx4){0.f, 0.f, 0.f, 0.f};
    float m_i[4], l_i[4];
    #pragma unroll
    for (int r = 0; r < 4; ++r) { m_i[r] = -1e30f; l_i[r] = 0.f; }

    const int wave_qmax = q0 + w * 16 + 15;

    for (int t0 = 0; t0 < q0 + BQ; t0 += BK) {
        __syncthreads();
        #pragma unroll
        for (int it = 0; it < 2; ++it) {
            int idx = tid + it * 256;
            int r = idx >> 4;
            int o = (idx & 15) << 3;
            uint4 d = *(const uint4*)(Kb + ((size_t)kv * T_SEQ + t0 + r) * HEAD_DIM + o);
            *(uint4*)&Ks[r][o] = d;
        }
        #pragma unroll
        for (int it = 0; it < 2; ++it) {
            int idx = tid + it * 256;
            int r = idx >> 2;
            int o = (idx & 3) << 3;
            uint4 d = *(const uint4*)(Vt + ((size_t)kv * HEAD_DIM + r) * T_SEQ + t0 + o);
            *(uint4*)&Vs[r][o] = d;
        }
        __syncthreads();
        if (t0 > wave_qmax) continue;

        floatx4 S[2];
        #pragma unroll
        for (int cb = 0; cb < 2; ++cb) {
            floatx4 a = (floatx4){0.f, 0.f, 0.f, 0.f};
            #pragma unroll
            for (int c = 0; c < 4; ++c) {
                short8 kf = *(const short8*)&Ks[cb * 16 + col][c * 32 + quad * 8];
                a = __builtin_amdgcn_mfma_f32_16x16x32_bf16(qf[c], kf, a, 0, 0, 0);
            }
            S[cb] = a;
        }

        const int qr_base = q0 + w * 16 + quad * 4;
        #pragma unroll
        for (int r = 0; r < 4; ++r) {
            const int qr = qr_base + r;
            #pragma unroll
            for (int cb = 0; cb < 2; ++cb) {
                int kt = t0 + cb * 16 + col;
                if (kt > qr) S[cb][r] = -1e30f;
            }
            float mx = fmaxf(S[0][r], S[1][r]);
            #pragma unroll
            for (int off = 1; off < 16; off <<= 1)
                mx = fmaxf(mx, __shfl_xor(mx, off, 64));
            const float mnew = fmaxf(m_i[r], mx);
            const float alpha = __expf(m_i[r] - mnew);
            m_i[r] = mnew;
            float rsum = 0.f;
            #pragma unroll
            for (int cb = 0; cb < 2; ++cb) {
                float p = __expf(S[cb][r] - mnew);
                unsigned short pb = f2bf(p);
                Ps[w][quad * 4 + r][cb * 16 + col] = pb;
                unsigned int pu = (unsigned int)pb << 16;
                rsum += __uint_as_float(pu);
            }
            #pragma unroll
            for (int off = 1; off < 16; off <<= 1)
                rsum += __shfl_xor(rsum, off, 64);
            l_i[r] = l_i[r] * alpha + rsum;
            #pragma unroll
            for (int cb = 0; cb < 8; ++cb) Ob[cb][r] *= alpha;
        }

        short8 pf = *(const short8*)&Ps[w][col][quad * 8];
        #pragma unroll
        for (int cb = 0; cb < 8; ++cb) {
            short8 vf = *(const short8*)&Vs[cb * 16 + col][quad * 8];
            Ob[cb] = __builtin_amdgcn_mfma_f32_16x16x32_bf16(pf, vf, Ob[cb], 0, 0, 0);
        }
    }

    #pragma unroll
    for (int r = 0; r < 4; ++r) {
        const float rl = 1.0f / l_i[r];
        const int qr = q0 + w * 16 + quad * 4 + r;
        #pragma unroll
        for (int cb = 0; cb < 8; ++cb)
            ctxb[(size_t)qr * Q_SIZE + h * HEAD_DIM + cb * 16 + col] = f2bf(Ob[cb][r] * rl);
    }
}

// ---------------------------------------------------------------------------
extern "C" void kernel_launch(void* const* d_in, const int* in_sizes, int n_in,
                              void* d_out, int out_size, void* d_ws, size_t ws_size,
                              hipStream_t stream)
{
    const int*   positions = (const int*)d_in[0];
    const float* hidden    = (const float*)d_in[1];
    const float* qkv_w     = (const float*)d_in[2];
    const float* q_norm_w  = (const float*)d_in[3];
    const float* k_norm_w  = (const float*)d_in[4];
    const float* o_w       = (const float*)d_in[5];
    float* out = (float*)d_out;

    const size_t MB = 1024 * 1024;
    char* ws = (char*)d_ws;
    float* qkv          = (float*)ws;                           // [0,32) MB
    unsigned short* Kb  = (unsigned short*)(ws + 32 * MB);      // [32,36)
    unsigned short* Vt  = (unsigned short*)(ws + 36 * MB);      // [36,40)
    unsigned short* hbf = (unsigned short*)(ws + 32 * MB);      // [32,40) (before Kb/Vt)
    unsigned short* wbf = (unsigned short*)(ws + 40 * MB);      // [40,56) (before ctxb/obf)
    unsigned short* ctxb= (unsigned short*)(ws + 40 * MB);      // [40,48)
    unsigned short* obf = (unsigned short*)(ws + 48 * MB);      // [48,56)

    // convert A and W to bf16
    f32_to_bf16<<<(T_SEQ * HIDDEN_ / 4 + 255) / 256, 256, 0, stream>>>(hidden, hbf, T_SEQ * HIDDEN_ / 4);
    f32_to_bf16<<<(QKV_N * HIDDEN_ / 4 + 255) / 256, 256, 0, stream>>>(qkv_w, wbf, QKV_N * HIDDEN_ / 4);
    // qkv = hidden @ qkv_w^T  (fp32 out)
    gemm_nt_bf16<<<dim3(QKV_N / 128, T_SEQ / 128), 256, 0, stream>>>(
        hbf, wbf, qkv, T_SEQ, QKV_N, HIDDEN_);
    normrope<<<dim3(T_SEQ, NUM_HEADS + NUM_KV), 128, 0, stream>>>(
        qkv, positions, q_norm_w, k_norm_w, Kb);
    convert_v<<<dim3(T_SEQ / 64, NUM_KV), 256, 0, stream>>>(qkv, Vt);
    attn_mfma<<<dim3(T_SEQ / BQ, NUM_HEADS), 256, 0, stream>>>(qkv, Kb, Vt, ctxb);
    // out = ctx @ o_w^T
    f32_to_bf16<<<(Q_SIZE * HIDDEN_ / 4 + 255) / 256, 256, 0, stream>>>(o_w, obf, Q_SIZE * HIDDEN_ / 4);
    gemm_nt_bf16<<<dim3(Q_SIZE / 128, T_SEQ / 128), 256, 0, stream>>>(
        ctxb, obf, out, T_SEQ, Q_SIZE, HIDDEN_);
}

// Round 4
// 317.915 us; speedup vs baseline: 10.6697x; 1.2412x over previous
//
#include <hip/hip_runtime.h>
#include <math.h>

#define T_SEQ     2048
#define HIDDEN_   2048
#define NUM_HEADS 16
#define NUM_KV    8
#define HEAD_DIM  128
#define Q_SIZE    2048
#define KV_SIZE   1024
#define QKV_N     4096
#define EPS_      1e-6f

typedef __attribute__((ext_vector_type(8))) short short8;
typedef __attribute__((ext_vector_type(4))) float floatx4;

__device__ __forceinline__ unsigned short f2bf(float f) {
    unsigned int u = __float_as_uint(f);
    u += 0x7fffu + ((u >> 16) & 1u);     // RNE
    return (unsigned short)(u >> 16);
}

__device__ __forceinline__ void stage16(const unsigned short* g, unsigned short* lds_base) {
    __builtin_amdgcn_global_load_lds(
        (const __attribute__((address_space(1))) unsigned int*)g,
        (__attribute__((address_space(3))) unsigned int*)lds_base, 16, 0, 0);
}

// ---------------------------------------------------------------------------
// fp32 -> bf16 bulk convert (n4 = element count / 4)
// ---------------------------------------------------------------------------
__global__ __launch_bounds__(256) void f32_to_bf16(
    const float* __restrict__ in, unsigned short* __restrict__ out, int n4)
{
    int i = blockIdx.x * 256 + threadIdx.x;
    if (i < n4) {
        float4 v = ((const float4*)in)[i];
        ushort4 o;
        o.x = f2bf(v.x); o.y = f2bf(v.y); o.z = f2bf(v.z); o.w = f2bf(v.w);
        ((ushort4*)out)[i] = o;
    }
}

// ---------------------------------------------------------------------------
// bf16 MFMA GEMM: C[M,N] fp32 = A[M,K]bf16 * B[N,K]bf16^T  (NT) — unchanged R3.
// ---------------------------------------------------------------------------
__global__ __launch_bounds__(256) void gemm_nt_bf16(
    const unsigned short* __restrict__ A, const unsigned short* __restrict__ B,
    float* __restrict__ C, int M, int N, int K)
{
    __shared__ unsigned short As[128 * 32];
    __shared__ unsigned short Bs[128 * 32];
    const int tid  = threadIdx.x;
    const int w    = tid >> 6;
    const int lane = tid & 63;
    const int col  = lane & 15;
    const int quad = lane >> 4;
    const int bm = blockIdx.y * 128;
    const int bn = blockIdx.x * 128;
    const int wm = (w & 1) * 64;
    const int wn = (w >> 1) * 64;

    floatx4 acc[4][4];
    #pragma unroll
    for (int i = 0; i < 4; ++i)
        #pragma unroll
        for (int j = 0; j < 4; ++j)
            acc[i][j] = (floatx4){0.f, 0.f, 0.f, 0.f};

    int s_r[2], s_lc[2];
    #pragma unroll
    for (int cc = 0; cc < 2; ++cc) {
        int s = cc * 256 + tid;
        int r = s >> 2, pc = s & 3;
        s_r[cc] = r;
        s_lc[cc] = pc ^ ((r >> 1) & 3);
    }

    for (int k0 = 0; k0 < K; k0 += 32) {
        __syncthreads();
        #pragma unroll
        for (int cc = 0; cc < 2; ++cc) {
            unsigned short* ldsA = &As[(cc * 256 + w * 64) * 8];
            unsigned short* ldsB = &Bs[(cc * 256 + w * 64) * 8];
            stage16(A + (size_t)(bm + s_r[cc]) * K + k0 + s_lc[cc] * 8, ldsA);
            stage16(B + (size_t)(bn + s_r[cc]) * K + k0 + s_lc[cc] * 8, ldsB);
        }
        __syncthreads();

        short8 af[4], bf[4];
        #pragma unroll
        for (int i = 0; i < 4; ++i) {
            int r = wm + i * 16 + col;
            int pc = quad ^ ((r >> 1) & 3);
            af[i] = *(const short8*)&As[r * 32 + pc * 8];
        }
        #pragma unroll
        for (int j = 0; j < 4; ++j) {
            int r = wn + j * 16 + col;
            int pc = quad ^ ((r >> 1) & 3);
            bf[j] = *(const short8*)&Bs[r * 32 + pc * 8];
        }
        #pragma unroll
        for (int i = 0; i < 4; ++i)
            #pragma unroll
            for (int j = 0; j < 4; ++j)
                acc[i][j] = __builtin_amdgcn_mfma_f32_16x16x32_bf16(af[i], bf[j], acc[i][j], 0, 0, 0);
    }

    #pragma unroll
    for (int i = 0; i < 4; ++i)
        #pragma unroll
        for (int j = 0; j < 4; ++j)
            #pragma unroll
            for (int rr = 0; rr < 4; ++rr) {
                int row = bm + wm + i * 16 + quad * 4 + rr;
                int cc2 = bn + wn + j * 16 + col;
                C[(size_t)row * N + cc2] = acc[i][j][rr];
            }
}

// ---------------------------------------------------------------------------
// Fused RMSNorm + RoPE — unchanged R3.
// ---------------------------------------------------------------------------
__global__ __launch_bounds__(128) void normrope(
    float* __restrict__ qkv, const int* __restrict__ positions,
    const float* __restrict__ qw, const float* __restrict__ kw,
    unsigned short* __restrict__ Kb)
{
    const int i = blockIdx.x;
    const int h = blockIdx.y;
    const int t = threadIdx.x;
    float* ptr;
    const float* w;
    if (h < NUM_HEADS) { ptr = qkv + (size_t)i * QKV_N + h * HEAD_DIM; w = qw; }
    else { ptr = qkv + (size_t)i * QKV_N + Q_SIZE + (h - NUM_HEADS) * HEAD_DIM; w = kw; }

    float x = ptr[t];
    float v = x * x;
    #pragma unroll
    for (int off = 32; off; off >>= 1) v += __shfl_xor(v, off, 64);
    __shared__ float sh[2];
    __shared__ float xn[HEAD_DIM];
    if ((t & 63) == 0) sh[t >> 6] = v;
    __syncthreads();
    const float sumsq = sh[0] + sh[1];
    const float inv = rsqrtf(sumsq * (1.0f / HEAD_DIM) + EPS_);
    xn[t] = x * inv * w[t];
    __syncthreads();

    const int d = t & 63;
    const float fr = (float)positions[i] * exp2f(-(float)d * (13.287712379549449f / 64.0f));
    float s, c;
    sincosf(fr, &s, &c);
    const float x1 = xn[d], x2 = xn[d + 64];
    const float val = (t < 64) ? (x1 * c - x2 * s) : (x2 * c + x1 * s);
    if (h < NUM_HEADS) ptr[t] = val;
    else Kb[((size_t)(h - NUM_HEADS) * T_SEQ + i) * HEAD_DIM + t] = f2bf(val);
}

// ---------------------------------------------------------------------------
// V: fp32 slice of qkv -> bf16 transposed Vt[kv][128][T] — unchanged R3.
// ---------------------------------------------------------------------------
__global__ __launch_bounds__(256) void convert_v(
    const float* __restrict__ qkv, unsigned short* __restrict__ Vt)
{
    const int kv = blockIdx.y;
    const int t0 = blockIdx.x * 64;
    const int tid = threadIdx.x;
    __shared__ unsigned short L[64][132];
    #pragma unroll
    for (int it = 0; it < 8; ++it) {
        int idx = tid + it * 256;
        int tl = idx >> 5;
        int c4 = idx & 31;
        float4 v = *(const float4*)(qkv + (size_t)(t0 + tl) * QKV_N
                                    + Q_SIZE + KV_SIZE + kv * HEAD_DIM + c4 * 4);
        ushort4 o;
        o.x = f2bf(v.x); o.y = f2bf(v.y); o.z = f2bf(v.z); o.w = f2bf(v.w);
        *(ushort4*)&L[tl][c4 * 4] = o;
    }
    __syncthreads();
    const int c = tid >> 1;
    const int half = tid & 1;
    unsigned short tmp[32] __attribute__((aligned(16)));
    #pragma unroll
    for (int s = 0; s < 32; ++s) tmp[s] = L[half * 32 + s][c];
    unsigned short* dst = Vt + ((size_t)kv * HEAD_DIM + c) * T_SEQ + t0 + half * 32;
    #pragma unroll
    for (int q = 0; q < 4; ++q)
        *(uint4*)(dst + q * 8) = *(const uint4*)(tmp + q * 8);
}

// ---------------------------------------------------------------------------
// Flash attention v2: fixed-max softmax (no reductions), ones-column l,
// XOR-swizzled conflict-free LDS, double-buffered global_load_lds staging.
// Block = (head, 64-query tile), 256 thr = 4 waves x 16 q-rows.
// ---------------------------------------------------------------------------
#define BQ 64
#define BK 32

__global__ __launch_bounds__(256) void attn_mfma(
    const float* __restrict__ qkv, const unsigned short* __restrict__ Kb,
    const unsigned short* __restrict__ Vt, unsigned short* __restrict__ ctxb)
{
    const int h = blockIdx.y;
    const int bx = blockIdx.x;
    const int qt = (bx & 1) ? (T_SEQ / BQ - 1 - (bx >> 1)) : (bx >> 1);
    const int q0 = qt * BQ;
    const int kv = h >> 1;
    const int tid = threadIdx.x;
    const int w = tid >> 6;
    const int lane = tid & 63;
    const int col = lane & 15;
    const int quad = lane >> 4;

    // K tile: 32 rows x 16 chunks(16B), chunk-swizzled: phys = j ^ (row&15)
    __shared__ unsigned short Ks[2][32 * 128];
    // V tile: 144 rows x 4 chunks; rows 0..127 staged (phys = j ^ (row&3)),
    // row 128 = ones (l-column), rows 129..143 = 0
    __shared__ unsigned short Vs[2][144 * 32];
    // P: per-wave [qrow 16][token 32], stride 40 shorts
    __shared__ unsigned short Ps[4][16][40];

    // init ones/zero rows of both V buffers (512 shorts each)
    {
        int x = 2 * tid;
        unsigned short val = (x < 32) ? (unsigned short)0x3F80 : (unsigned short)0;
        unsigned int vv = (unsigned int)val | ((unsigned int)val << 16);
        ((unsigned int*)&Vs[0][128 * 32])[tid] = vv;
        ((unsigned int*)&Vs[1][128 * 32])[tid] = vv;
    }

    // Q fragments (B-operand): rows = q-row (col), k = quad*8+j; scale folded in
    short8 qf[4];
    {
        const float* qp = qkv + (size_t)(q0 + w * 16 + col) * QKV_N + h * HEAD_DIM;
        #pragma unroll
        for (int c = 0; c < 4; ++c) {
            const float* p = qp + c * 32 + quad * 8;
            float4 a = *(const float4*)p;
            float4 b = *(const float4*)(p + 4);
            const float sc = 0.08838834764831845f;   // 1/sqrt(128)
            qf[c][0] = (short)f2bf(a.x * sc); qf[c][1] = (short)f2bf(a.y * sc);
            qf[c][2] = (short)f2bf(a.z * sc); qf[c][3] = (short)f2bf(a.w * sc);
            qf[c][4] = (short)f2bf(b.x * sc); qf[c][5] = (short)f2bf(b.y * sc);
            qf[c][6] = (short)f2bf(b.z * sc); qf[c][7] = (short)f2bf(b.w * sc);
        }
    }

    // per-lane staging sources
    const unsigned short* kg[2];
    const unsigned short* vg[2];
    #pragma unroll
    for (int it = 0; it < 2; ++it) {
        int s = it * 256 + w * 64 + lane;
        int kr = s >> 4, kp = s & 15, kj = kp ^ (kr & 15);
        kg[it] = Kb + (size_t)kv * T_SEQ * HEAD_DIM + kr * HEAD_DIM + kj * 8;
        int vr = s >> 2, vp = s & 3, vj = vp ^ (vr & 3);
        vg[it] = Vt + (size_t)kv * HEAD_DIM * T_SEQ + (size_t)vr * T_SEQ + vj * 8;
    }

    floatx4 Ob[9];
    #pragma unroll
    for (int cb = 0; cb < 9; ++cb) Ob[cb] = (floatx4){0.f, 0.f, 0.f, 0.f};

    const int wave_qmax = q0 + w * 16 + 15;
    const int nt = q0 / BK + 2;

    // prefetch tile 0
    #pragma unroll
    for (int it = 0; it < 2; ++it) {
        stage16(kg[it], &Ks[0][(it * 256 + w * 64) * 8]);
        stage16(vg[it], &Vs[0][(it * 256 + w * 64) * 8]);
    }

    for (int i = 0; i < nt; ++i) {
        const int t0 = i * BK;
        __syncthreads();                      // tile i ready; buffers free
        if (i + 1 < nt) {
            const int tn = t0 + BK;
            const int b = (i + 1) & 1;
            #pragma unroll
            for (int it = 0; it < 2; ++it) {
                stage16(kg[it] + (size_t)tn * HEAD_DIM, &Ks[b][(it * 256 + w * 64) * 8]);
                stage16(vg[it] + tn, &Vs[b][(it * 256 + w * 64) * 8]);
            }
        }
        if (t0 > wave_qmax) continue;         // wave-uniform skip
        const unsigned short* ks = Ks[i & 1];
        const unsigned short* vs = Vs[i & 1];

        // S^T = K Q^T : rows = tokens (quad*4+r), cols = q-rows (col)
        floatx4 S[2];
        #pragma unroll
        for (int cb = 0; cb < 2; ++cb) {
            floatx4 a = (floatx4){0.f, 0.f, 0.f, 0.f};
            #pragma unroll
            for (int c = 0; c < 4; ++c) {
                short8 kf = *(const short8*)&ks[((cb * 16 + col) * 16 + ((c * 4 + quad) ^ col)) * 8];
                a = __builtin_amdgcn_mfma_f32_16x16x32_bf16(kf, qf[c], a, 0, 0, 0);
            }
            S[cb] = a;
        }

        // fixed-max softmax numerator: p = masked ? 0 : exp(s); pack 4 tokens
        const int qr = q0 + w * 16 + col;
        #pragma unroll
        for (int cb = 0; cb < 2; ++cb) {
            ushort4 pk;
            {
                int kt = t0 + cb * 16 + quad * 4;
                float p0 = (kt + 0 <= qr) ? __expf(S[cb][0]) : 0.f;
                float p1 = (kt + 1 <= qr) ? __expf(S[cb][1]) : 0.f;
                float p2 = (kt + 2 <= qr) ? __expf(S[cb][2]) : 0.f;
                float p3 = (kt + 3 <= qr) ? __expf(S[cb][3]) : 0.f;
                pk.x = f2bf(p0); pk.y = f2bf(p1); pk.z = f2bf(p2); pk.w = f2bf(p3);
            }
            *(ushort4*)&Ps[w][col][cb * 16 + quad * 4] = pk;
        }

        // PV (+ ones column -> l in Ob[8] col 0)
        short8 pf = *(const short8*)&Ps[w][col][quad * 8];
        #pragma unroll
        for (int cb = 0; cb < 9; ++cb) {
            int vrow = cb * 16 + col;
            short8 vf = *(const short8*)&vs[(vrow * 4 + (quad ^ (vrow & 3))) * 8];
            Ob[cb] = __builtin_amdgcn_mfma_f32_16x16x32_bf16(pf, vf, Ob[cb], 0, 0, 0);
        }
    }

    // epilogue: divide by l (broadcast from col-0 lane of each quad)
    #pragma unroll
    for (int r = 0; r < 4; ++r) {
        float l = __shfl(Ob[8][r], lane & 48);
        float rl = 1.0f / l;
        const int qr = q0 + w * 16 + quad * 4 + r;
        #pragma unroll
        for (int cb = 0; cb < 8; ++cb)
            ctxb[(size_t)qr * Q_SIZE + h * HEAD_DIM + cb * 16 + col] = f2bf(Ob[cb][r] * rl);
    }
}

// ---------------------------------------------------------------------------
extern "C" void kernel_launch(void* const* d_in, const int* in_sizes, int n_in,
                              void* d_out, int out_size, void* d_ws, size_t ws_size,
                              hipStream_t stream)
{
    const int*   positions = (const int*)d_in[0];
    const float* hidden    = (const float*)d_in[1];
    const float* qkv_w     = (const float*)d_in[2];
    const float* q_norm_w  = (const float*)d_in[3];
    const float* k_norm_w  = (const float*)d_in[4];
    const float* o_w       = (const float*)d_in[5];
    float* out = (float*)d_out;

    const size_t MB = 1024 * 1024;
    char* ws = (char*)d_ws;
    float* qkv          = (float*)ws;                           // [0,32) MB
    unsigned short* Kb  = (unsigned short*)(ws + 32 * MB);      // [32,36)
    unsigned short* Vt  = (unsigned short*)(ws + 36 * MB);      // [36,40)
    unsigned short* hbf = (unsigned short*)(ws + 32 * MB);      // [32,40) (before Kb/Vt)
    unsigned short* wbf = (unsigned short*)(ws + 40 * MB);      // [40,56) (before ctxb/obf)
    unsigned short* ctxb= (unsigned short*)(ws + 40 * MB);      // [40,48)
    unsigned short* obf = (unsigned short*)(ws + 48 * MB);      // [48,56)

    f32_to_bf16<<<(T_SEQ * HIDDEN_ / 4 + 255) / 256, 256, 0, stream>>>(hidden, hbf, T_SEQ * HIDDEN_ / 4);
    f32_to_bf16<<<(QKV_N * HIDDEN_ / 4 + 255) / 256, 256, 0, stream>>>(qkv_w, wbf, QKV_N * HIDDEN_ / 4);
    gemm_nt_bf16<<<dim3(QKV_N / 128, T_SEQ / 128), 256, 0, stream>>>(
        hbf, wbf, qkv, T_SEQ, QKV_N, HIDDEN_);
    normrope<<<dim3(T_SEQ, NUM_HEADS + NUM_KV), 128, 0, stream>>>(
        qkv, positions, q_norm_w, k_norm_w, Kb);
    convert_v<<<dim3(T_SEQ / 64, NUM_KV), 256, 0, stream>>>(qkv, Vt);
    attn_mfma<<<dim3(T_SEQ / BQ, NUM_HEADS), 256, 0, stream>>>(qkv, Kb, Vt, ctxb);
    f32_to_bf16<<<(Q_SIZE * HIDDEN_ / 4 + 255) / 256, 256, 0, stream>>>(o_w, obf, Q_SIZE * HIDDEN_ / 4);
    gemm_nt_bf16<<<dim3(Q_SIZE / 128, T_SEQ / 128), 256, 0, stream>>>(
        ctxb, obf, out, T_SEQ, Q_SIZE, HIDDEN_);
}

// Round 5
// 311.130 us; speedup vs baseline: 10.9024x; 1.0218x over previous
//
#include <hip/hip_runtime.h>
#include <math.h>

#define T_SEQ     2048
#define HIDDEN_   2048
#define NUM_HEADS 16
#define NUM_KV    8
#define HEAD_DIM  128
#define Q_SIZE    2048
#define KV_SIZE   1024
#define QKV_N     4096
#define EPS_      1e-6f

typedef __attribute__((ext_vector_type(8))) short short8;
typedef __attribute__((ext_vector_type(4))) float floatx4;

__device__ __forceinline__ unsigned short f2bf(float f) {
    unsigned int u = __float_as_uint(f);
    u += 0x7fffu + ((u >> 16) & 1u);     // RNE
    return (unsigned short)(u >> 16);
}

__device__ __forceinline__ void stage16(const unsigned short* g, unsigned short* lds_base) {
    __builtin_amdgcn_global_load_lds(
        (const __attribute__((address_space(1))) unsigned int*)g,
        (__attribute__((address_space(3))) unsigned int*)lds_base, 16, 0, 0);
}

// ---------------------------------------------------------------------------
// fp32 -> bf16 bulk convert (n4 = element count / 4)
// ---------------------------------------------------------------------------
__global__ __launch_bounds__(256) void f32_to_bf16(
    const float* __restrict__ in, unsigned short* __restrict__ out, int n4)
{
    int i = blockIdx.x * 256 + threadIdx.x;
    if (i < n4) {
        float4 v = ((const float4*)in)[i];
        ushort4 o;
        o.x = f2bf(v.x); o.y = f2bf(v.y); o.z = f2bf(v.z); o.w = f2bf(v.w);
        ((ushort4*)out)[i] = o;
    }
}

// ---------------------------------------------------------------------------
// bf16 MFMA GEMM: C[M,N] fp32 = A[M,K]bf16 * B[N,K]bf16^T  (NT) — unchanged.
// ---------------------------------------------------------------------------
__global__ __launch_bounds__(256) void gemm_nt_bf16(
    const unsigned short* __restrict__ A, const unsigned short* __restrict__ B,
    float* __restrict__ C, int M, int N, int K)
{
    __shared__ unsigned short As[128 * 32];
    __shared__ unsigned short Bs[128 * 32];
    const int tid  = threadIdx.x;
    const int w    = tid >> 6;
    const int lane = tid & 63;
    const int col  = lane & 15;
    const int quad = lane >> 4;
    const int bm = blockIdx.y * 128;
    const int bn = blockIdx.x * 128;
    const int wm = (w & 1) * 64;
    const int wn = (w >> 1) * 64;

    floatx4 acc[4][4];
    #pragma unroll
    for (int i = 0; i < 4; ++i)
        #pragma unroll
        for (int j = 0; j < 4; ++j)
            acc[i][j] = (floatx4){0.f, 0.f, 0.f, 0.f};

    int s_r[2], s_lc[2];
    #pragma unroll
    for (int cc = 0; cc < 2; ++cc) {
        int s = cc * 256 + tid;
        int r = s >> 2, pc = s & 3;
        s_r[cc] = r;
        s_lc[cc] = pc ^ ((r >> 1) & 3);
    }

    for (int k0 = 0; k0 < K; k0 += 32) {
        __syncthreads();
        #pragma unroll
        for (int cc = 0; cc < 2; ++cc) {
            unsigned short* ldsA = &As[(cc * 256 + w * 64) * 8];
            unsigned short* ldsB = &Bs[(cc * 256 + w * 64) * 8];
            stage16(A + (size_t)(bm + s_r[cc]) * K + k0 + s_lc[cc] * 8, ldsA);
            stage16(B + (size_t)(bn + s_r[cc]) * K + k0 + s_lc[cc] * 8, ldsB);
        }
        __syncthreads();

        short8 af[4], bf[4];
        #pragma unroll
        for (int i = 0; i < 4; ++i) {
            int r = wm + i * 16 + col;
            int pc = quad ^ ((r >> 1) & 3);
            af[i] = *(const short8*)&As[r * 32 + pc * 8];
        }
        #pragma unroll
        for (int j = 0; j < 4; ++j) {
            int r = wn + j * 16 + col;
            int pc = quad ^ ((r >> 1) & 3);
            bf[j] = *(const short8*)&Bs[r * 32 + pc * 8];
        }
        #pragma unroll
        for (int i = 0; i < 4; ++i)
            #pragma unroll
            for (int j = 0; j < 4; ++j)
                acc[i][j] = __builtin_amdgcn_mfma_f32_16x16x32_bf16(af[i], bf[j], acc[i][j], 0, 0, 0);
    }

    #pragma unroll
    for (int i = 0; i < 4; ++i)
        #pragma unroll
        for (int j = 0; j < 4; ++j)
            #pragma unroll
            for (int rr = 0; rr < 4; ++rr) {
                int row = bm + wm + i * 16 + quad * 4 + rr;
                int cc2 = bn + wn + j * 16 + col;
                C[(size_t)row * N + cc2] = acc[i][j][rr];
            }
}

// ---------------------------------------------------------------------------
// Fused RMSNorm + RoPE. q heads -> bf16 Qb[T][2048] with 1/sqrt(D) folded;
// k heads -> bf16 Kb[kv][T][128].
// ---------------------------------------------------------------------------
__global__ __launch_bounds__(128) void normrope(
    const float* __restrict__ qkv, const int* __restrict__ positions,
    const float* __restrict__ qw, const float* __restrict__ kw,
    unsigned short* __restrict__ Qb, unsigned short* __restrict__ Kb)
{
    const int i = blockIdx.x;
    const int h = blockIdx.y;
    const int t = threadIdx.x;
    const float* ptr;
    const float* w;
    if (h < NUM_HEADS) { ptr = qkv + (size_t)i * QKV_N + h * HEAD_DIM; w = qw; }
    else { ptr = qkv + (size_t)i * QKV_N + Q_SIZE + (h - NUM_HEADS) * HEAD_DIM; w = kw; }

    float x = ptr[t];
    float v = x * x;
    #pragma unroll
    for (int off = 32; off; off >>= 1) v += __shfl_xor(v, off, 64);
    __shared__ float sh[2];
    __shared__ float xn[HEAD_DIM];
    if ((t & 63) == 0) sh[t >> 6] = v;
    __syncthreads();
    const float sumsq = sh[0] + sh[1];
    const float inv = rsqrtf(sumsq * (1.0f / HEAD_DIM) + EPS_);
    xn[t] = x * inv * w[t];
    __syncthreads();

    const int d = t & 63;
    const float fr = (float)positions[i] * exp2f(-(float)d * (13.287712379549449f / 64.0f));
    float s, c;
    sincosf(fr, &s, &c);
    const float x1 = xn[d], x2 = xn[d + 64];
    const float val = (t < 64) ? (x1 * c - x2 * s) : (x2 * c + x1 * s);
    if (h < NUM_HEADS)
        Qb[(size_t)i * Q_SIZE + h * HEAD_DIM + t] = f2bf(val * 0.08838834764831845f);
    else
        Kb[((size_t)(h - NUM_HEADS) * T_SEQ + i) * HEAD_DIM + t] = f2bf(val);
}

// ---------------------------------------------------------------------------
// V: fp32 slice of qkv -> bf16 transposed Vt[kv][128][T] — unchanged.
// ---------------------------------------------------------------------------
__global__ __launch_bounds__(256) void convert_v(
    const float* __restrict__ qkv, unsigned short* __restrict__ Vt)
{
    const int kv = blockIdx.y;
    const int t0 = blockIdx.x * 64;
    const int tid = threadIdx.x;
    __shared__ unsigned short L[64][132];
    #pragma unroll
    for (int it = 0; it < 8; ++it) {
        int idx = tid + it * 256;
        int tl = idx >> 5;
        int c4 = idx & 31;
        float4 v = *(const float4*)(qkv + (size_t)(t0 + tl) * QKV_N
                                    + Q_SIZE + KV_SIZE + kv * HEAD_DIM + c4 * 4);
        ushort4 o;
        o.x = f2bf(v.x); o.y = f2bf(v.y); o.z = f2bf(v.z); o.w = f2bf(v.w);
        *(ushort4*)&L[tl][c4 * 4] = o;
    }
    __syncthreads();
    const int c = tid >> 1;
    const int half = tid & 1;
    unsigned short tmp[32] __attribute__((aligned(16)));
    #pragma unroll
    for (int s = 0; s < 32; ++s) tmp[s] = L[half * 32 + s][c];
    unsigned short* dst = Vt + ((size_t)kv * HEAD_DIM + c) * T_SEQ + t0 + half * 32;
    #pragma unroll
    for (int q = 0; q < 4; ++q)
        *(uint4*)(dst + q * 8) = *(const uint4*)(tmp + q * 8);
}

// ---------------------------------------------------------------------------
// Flash attention v3: BK=64, split-K over 1024-token chunks (linear partials),
// fixed-max softmax, ones-column l, heavy-first block ordering.
// grid.x = 48 work items per head: x<16 -> (qt=16+x, ch=0); else pairs of
// (qt=15-p, ch=0) / (qt=31-p, ch=1) descending.
// ---------------------------------------------------------------------------
#define BQ 64
#define BK 64

__global__ __launch_bounds__(256) void attn_mfma(
    const unsigned short* __restrict__ Qb, const unsigned short* __restrict__ Kb,
    const unsigned short* __restrict__ Vt, unsigned short* __restrict__ ctxb,
    float* __restrict__ partO, float* __restrict__ partL)
{
    const int h = blockIdx.y;
    int qt, ch;
    {
        int x = blockIdx.x;
        if (x < 16) { qt = 16 + x; ch = 0; }
        else {
            int p = (x - 16) >> 1;
            if (((x - 16) & 1) == 0) { qt = 15 - p; ch = 0; }
            else                     { qt = 31 - p; ch = 1; }
        }
    }
    const int nch = (qt >= 16) ? 2 : 1;
    const int units = (ch == 0) ? ((qt + 1 < 16) ? qt + 1 : 16) : (qt + 1 - 16);
    const int q0 = qt * BQ;
    const int kv = h >> 1;
    const int tid = threadIdx.x;
    const int w = tid >> 6;
    const int lane = tid & 63;
    const int col = lane & 15;
    const int quad = lane >> 4;

    __shared__ unsigned short Ks[2][64 * 128];   // [tok][d] chunk-swizzled ^(row&15)
    __shared__ unsigned short Vs[2][144 * 64];   // [d][tok] chunk-swizzled ^(row&7); row128=ones
    __shared__ unsigned short Ps[4][16][72];

    // ones / zero rows of V (rows 128..143), swizzle-invariant (constant rows)
    {
        int x = tid * 4;
        unsigned short vv = (x < 64) ? (unsigned short)0x3F80 : (unsigned short)0;
        ushort4 o = {vv, vv, vv, vv};
        *(ushort4*)&Vs[0][128 * 64 + x] = o;
        *(ushort4*)&Vs[1][128 * 64 + x] = o;
    }

    // Q fragments from Qb (scale pre-folded)
    short8 qf[4];
    {
        const unsigned short* qp = Qb + (size_t)(q0 + w * 16 + col) * Q_SIZE + h * HEAD_DIM;
        #pragma unroll
        for (int c = 0; c < 4; ++c)
            qf[c] = *(const short8*)(qp + c * 32 + quad * 8);
    }

    // staging source bases (per-lane, 4 slots each of K and V)
    const unsigned short* kg[4];
    const unsigned short* vg[4];
    #pragma unroll
    for (int it = 0; it < 4; ++it) {
        int s = it * 256 + tid;
        int kr = s >> 4, kp = s & 15, kj = kp ^ (kr & 15);
        kg[it] = Kb + (size_t)kv * T_SEQ * HEAD_DIM + kr * HEAD_DIM + kj * 8;
        int vr = s >> 3, vp = s & 7, vj = vp ^ (vr & 7);
        vg[it] = Vt + (size_t)kv * HEAD_DIM * T_SEQ + (size_t)vr * T_SEQ + vj * 8;
    }

    floatx4 Ob[9];
    #pragma unroll
    for (int cb = 0; cb < 9; ++cb) Ob[cb] = (floatx4){0.f, 0.f, 0.f, 0.f};

    const int wave_qmin = q0 + w * 16;
    const int wave_qmax = wave_qmin + 15;
    const int tok_base = ch * 1024;

    // prefetch unit 0
    #pragma unroll
    for (int it = 0; it < 4; ++it) {
        stage16(kg[it] + (size_t)tok_base * HEAD_DIM, &Ks[0][(it * 256 + w * 64) * 8]);
        stage16(vg[it] + tok_base, &Vs[0][(it * 256 + w * 64) * 8]);
    }

    for (int u = 0; u < units; ++u) {
        const int t0 = tok_base + u * BK;
        __syncthreads();
        if (u + 1 < units) {
            const int tn = t0 + BK;
            const int b = (u + 1) & 1;
            #pragma unroll
            for (int it = 0; it < 4; ++it) {
                stage16(kg[it] + (size_t)tn * HEAD_DIM, &Ks[b][(it * 256 + w * 64) * 8]);
                stage16(vg[it] + tn, &Vs[b][(it * 256 + w * 64) * 8]);
            }
        }
        if (t0 > wave_qmax) continue;          // wave-uniform skip (last chunk only)
        const unsigned short* ks = Ks[u & 1];
        const unsigned short* vs = Vs[u & 1];

        // S^T = K Q^T : 4 row-blocks of 16 tokens
        floatx4 S[4];
        #pragma unroll
        for (int cb = 0; cb < 4; ++cb) {
            floatx4 a = (floatx4){0.f, 0.f, 0.f, 0.f};
            #pragma unroll
            for (int c = 0; c < 4; ++c) {
                short8 kf = *(const short8*)&ks[((cb * 16 + col) * 16 + ((c * 4 + quad) ^ col)) * 8];
                a = __builtin_amdgcn_mfma_f32_16x16x32_bf16(kf, qf[c], a, 0, 0, 0);
            }
            S[cb] = a;
        }

        // fixed-max numerator p = exp(s) (mask only on diagonal tiles)
        const int qr = q0 + w * 16 + col;
        if (t0 + 63 <= wave_qmin) {
            #pragma unroll
            for (int cb = 0; cb < 4; ++cb) {
                ushort4 pk;
                pk.x = f2bf(__expf(S[cb][0])); pk.y = f2bf(__expf(S[cb][1]));
                pk.z = f2bf(__expf(S[cb][2])); pk.w = f2bf(__expf(S[cb][3]));
                *(ushort4*)&Ps[w][col][cb * 16 + quad * 4] = pk;
            }
        } else {
            #pragma unroll
            for (int cb = 0; cb < 4; ++cb) {
                int kt = t0 + cb * 16 + quad * 4;
                ushort4 pk;
                pk.x = (kt + 0 <= qr) ? f2bf(__expf(S[cb][0])) : (unsigned short)0;
                pk.y = (kt + 1 <= qr) ? f2bf(__expf(S[cb][1])) : (unsigned short)0;
                pk.z = (kt + 2 <= qr) ? f2bf(__expf(S[cb][2])) : (unsigned short)0;
                pk.w = (kt + 3 <= qr) ? f2bf(__expf(S[cb][3])) : (unsigned short)0;
                *(ushort4*)&Ps[w][col][cb * 16 + quad * 4] = pk;
            }
        }

        // PV (+ ones row -> l in Ob[8] col 0); same-wave LDS in-order
        short8 pf[2];
        pf[0] = *(const short8*)&Ps[w][col][quad * 8];
        pf[1] = *(const short8*)&Ps[w][col][32 + quad * 8];
        #pragma unroll
        for (int cb = 0; cb < 9; ++cb) {
            int vrow = cb * 16 + col;
            #pragma unroll
            for (int kk = 0; kk < 2; ++kk) {
                short8 vf = *(const short8*)&vs[(vrow * 8 + ((kk * 4 + quad) ^ (vrow & 7))) * 8];
                Ob[cb] = __builtin_amdgcn_mfma_f32_16x16x32_bf16(pf[kk], vf, Ob[cb], 0, 0, 0);
            }
        }
    }

    if (nch == 1) {
        #pragma unroll
        for (int r = 0; r < 4; ++r) {
            float l = __shfl(Ob[8][r], lane & 48);
            float rl = 1.0f / l;
            const int qrow = q0 + w * 16 + quad * 4 + r;
            #pragma unroll
            for (int cb = 0; cb < 8; ++cb)
                ctxb[(size_t)qrow * Q_SIZE + h * HEAD_DIM + cb * 16 + col] = f2bf(Ob[cb][r] * rl);
        }
    } else {
        const int slot = (h * 16 + (qt - 16)) * 2 + ch;
        float* po = partO + (size_t)slot * (BQ * HEAD_DIM);
        #pragma unroll
        for (int cb = 0; cb < 8; ++cb)
            #pragma unroll
            for (int r = 0; r < 4; ++r)
                po[(w * 16 + quad * 4 + r) * HEAD_DIM + cb * 16 + col] = Ob[cb][r];
        if (col == 0) {
            #pragma unroll
            for (int r = 0; r < 4; ++r)
                partL[slot * BQ + w * 16 + quad * 4 + r] = Ob[8][r];
        }
    }
}

// ---------------------------------------------------------------------------
// Combine: ctx[qt>=16] = (O0 + O1) / (l0 + l1), write bf16.
// grid = 16 heads * 16 qt, 256 threads.
// ---------------------------------------------------------------------------
__global__ __launch_bounds__(256) void combine(
    const float* __restrict__ partO, const float* __restrict__ partL,
    unsigned short* __restrict__ ctxb)
{
    const int h = blockIdx.x >> 4;
    const int qi = blockIdx.x & 15;
    const int q0 = (16 + qi) * 64;
    const int slot0 = (h * 16 + qi) * 2;
    const int tid = threadIdx.x;
    const int row = tid >> 2;
    const int seg = tid & 3;

    const float l = partL[slot0 * 64 + row] + partL[(slot0 + 1) * 64 + row];
    const float rl = 1.0f / l;
    const float* p0 = partO + (size_t)slot0 * 8192 + row * 128 + seg * 32;
    const float* p1 = p0 + 8192;
    unsigned short* dst = ctxb + (size_t)(q0 + row) * Q_SIZE + h * HEAD_DIM + seg * 32;
    #pragma unroll
    for (int m = 0; m < 8; ++m) {
        float4 a = *(const float4*)(p0 + m * 4);
        float4 b = *(const float4*)(p1 + m * 4);
        ushort4 o;
        o.x = f2bf((a.x + b.x) * rl); o.y = f2bf((a.y + b.y) * rl);
        o.z = f2bf((a.z + b.z) * rl); o.w = f2bf((a.w + b.w) * rl);
        *(ushort4*)(dst + m * 4) = o;
    }
}

// ---------------------------------------------------------------------------
extern "C" void kernel_launch(void* const* d_in, const int* in_sizes, int n_in,
                              void* d_out, int out_size, void* d_ws, size_t ws_size,
                              hipStream_t stream)
{
    const int*   positions = (const int*)d_in[0];
    const float* hidden    = (const float*)d_in[1];
    const float* qkv_w     = (const float*)d_in[2];
    const float* q_norm_w  = (const float*)d_in[3];
    const float* k_norm_w  = (const float*)d_in[4];
    const float* o_w       = (const float*)d_in[5];
    float* out = (float*)d_out;

    const size_t MB = 1024 * 1024;
    char* ws = (char*)d_ws;
    float* qkv           = (float*)ws;                          // [0,32) GEMM out (dead after convert_v)
    float* partO         = (float*)ws;                          // [0,16.78) over dead qkv
    float* partL         = (float*)(ws + 16777216);             // +128 KB
    unsigned short* obf  = (unsigned short*)(ws + 17 * MB);     // [17,25) over dead qkv
    unsigned short* Kb   = (unsigned short*)(ws + 32 * MB);     // [32,36)
    unsigned short* Vt   = (unsigned short*)(ws + 36 * MB);     // [36,40)
    unsigned short* hbf  = (unsigned short*)(ws + 32 * MB);     // [32,40) dead before Kb/Vt
    unsigned short* wbf  = (unsigned short*)(ws + 40 * MB);     // [40,56) dead after GEMM
    unsigned short* Qb   = (unsigned short*)(ws + 40 * MB);     // [40,48) over dead wbf
    unsigned short* ctxb = (unsigned short*)(ws + 48 * MB);     // [48,56)

    f32_to_bf16<<<(T_SEQ * HIDDEN_ / 4 + 255) / 256, 256, 0, stream>>>(hidden, hbf, T_SEQ * HIDDEN_ / 4);
    f32_to_bf16<<<(QKV_N * HIDDEN_ / 4 + 255) / 256, 256, 0, stream>>>(qkv_w, wbf, QKV_N * HIDDEN_ / 4);
    gemm_nt_bf16<<<dim3(QKV_N / 128, T_SEQ / 128), 256, 0, stream>>>(
        hbf, wbf, qkv, T_SEQ, QKV_N, HIDDEN_);
    normrope<<<dim3(T_SEQ, NUM_HEADS + NUM_KV), 128, 0, stream>>>(
        qkv, positions, q_norm_w, k_norm_w, Qb, Kb);
    convert_v<<<dim3(T_SEQ / 64, NUM_KV), 256, 0, stream>>>(qkv, Vt);
    f32_to_bf16<<<(Q_SIZE * HIDDEN_ / 4 + 255) / 256, 256, 0, stream>>>(o_w, obf, Q_SIZE * HIDDEN_ / 4);
    attn_mfma<<<dim3(48, NUM_HEADS), 256, 0, stream>>>(Qb, Kb, Vt, ctxb, partO, partL);
    combine<<<256, 256, 0, stream>>>(partO, partL, ctxb);
    gemm_nt_bf16<<<dim3(Q_SIZE / 128, T_SEQ / 128), 256, 0, stream>>>(
        ctxb, obf, out, T_SEQ, Q_SIZE, HIDDEN_);
}

// Round 6
// 298.891 us; speedup vs baseline: 11.3489x; 1.0410x over previous
//
#include <hip/hip_runtime.h>
#include <math.h>

#define T_SEQ     2048
#define HIDDEN_   2048
#define NUM_HEADS 16
#define NUM_KV    8
#define HEAD_DIM  128
#define Q_SIZE    2048
#define KV_SIZE   1024
#define QKV_N     4096
#define QK_N      3072
#define EPS_      1e-6f

typedef __attribute__((ext_vector_type(8))) short short8;
typedef __attribute__((ext_vector_type(4))) float floatx4;

__device__ __forceinline__ unsigned short f2bf(float f) {
    unsigned int u = __float_as_uint(f);
    u += 0x7fffu + ((u >> 16) & 1u);     // RNE
    return (unsigned short)(u >> 16);
}
__device__ __forceinline__ float b2f(unsigned short u) {
    return __uint_as_float((unsigned int)u << 16);
}

__device__ __forceinline__ void stage16(const unsigned short* g, unsigned short* lds_base) {
    __builtin_amdgcn_global_load_lds(
        (const __attribute__((address_space(1))) unsigned int*)g,
        (__attribute__((address_space(3))) unsigned int*)lds_base, 16, 0, 0);
}

// ---------------------------------------------------------------------------
// Fused fp32 -> bf16 conversion of hidden, qkv_w, o_w in ONE launch.
// ---------------------------------------------------------------------------
#define H4 (T_SEQ * HIDDEN_ / 4)
#define W4 (QKV_N * HIDDEN_ / 4)
#define O4 (Q_SIZE * HIDDEN_ / 4)

__global__ __launch_bounds__(256) void convert_all(
    const float* __restrict__ hidden, const float* __restrict__ qkv_w,
    const float* __restrict__ o_w, unsigned short* __restrict__ hbf,
    unsigned short* __restrict__ wbf, unsigned short* __restrict__ obf)
{
    int i = blockIdx.x * 256 + threadIdx.x;
    const float4* src;
    ushort4* dst;
    int j;
    if (i < H4)            { src = (const float4*)hidden; dst = (ushort4*)hbf; j = i; }
    else if (i < H4 + W4)  { src = (const float4*)qkv_w;  dst = (ushort4*)wbf; j = i - H4; }
    else                   { src = (const float4*)o_w;    dst = (ushort4*)obf; j = i - H4 - W4;
                             if (j >= O4) return; }
    float4 v = src[j];
    ushort4 o;
    o.x = f2bf(v.x); o.y = f2bf(v.y); o.z = f2bf(v.z); o.w = f2bf(v.w);
    dst[j] = o;
}

// ---------------------------------------------------------------------------
// bf16 MFMA GEMM (NT). MODE 0: C fp32 row-major.
// MODE 1 (QKV): cols < 3072 -> bf16 qkvb[T][3072]; cols >= 3072 -> bf16
// transposed Vt[kv][128][T] (replaces convert_v).
// ---------------------------------------------------------------------------
template<int MODE>
__global__ __launch_bounds__(256) void gemm_nt_bf16(
    const unsigned short* __restrict__ A, const unsigned short* __restrict__ B,
    float* __restrict__ C, unsigned short* __restrict__ qkvb,
    unsigned short* __restrict__ Vt, int M, int N, int K)
{
    __shared__ unsigned short As[128 * 32];
    __shared__ unsigned short Bs[128 * 32];
    const int tid  = threadIdx.x;
    const int w    = tid >> 6;
    const int lane = tid & 63;
    const int col  = lane & 15;
    const int quad = lane >> 4;
    const int bm = blockIdx.y * 128;
    const int bn = blockIdx.x * 128;
    const int wm = (w & 1) * 64;
    const int wn = (w >> 1) * 64;

    floatx4 acc[4][4];
    #pragma unroll
    for (int i = 0; i < 4; ++i)
        #pragma unroll
        for (int j = 0; j < 4; ++j)
            acc[i][j] = (floatx4){0.f, 0.f, 0.f, 0.f};

    int s_r[2], s_lc[2];
    #pragma unroll
    for (int cc = 0; cc < 2; ++cc) {
        int s = cc * 256 + tid;
        int r = s >> 2, pc = s & 3;
        s_r[cc] = r;
        s_lc[cc] = pc ^ ((r >> 1) & 3);
    }

    for (int k0 = 0; k0 < K; k0 += 32) {
        __syncthreads();
        #pragma unroll
        for (int cc = 0; cc < 2; ++cc) {
            unsigned short* ldsA = &As[(cc * 256 + w * 64) * 8];
            unsigned short* ldsB = &Bs[(cc * 256 + w * 64) * 8];
            stage16(A + (size_t)(bm + s_r[cc]) * K + k0 + s_lc[cc] * 8, ldsA);
            stage16(B + (size_t)(bn + s_r[cc]) * K + k0 + s_lc[cc] * 8, ldsB);
        }
        __syncthreads();

        short8 af[4], bf[4];
        #pragma unroll
        for (int i = 0; i < 4; ++i) {
            int r = wm + i * 16 + col;
            int pc = quad ^ ((r >> 1) & 3);
            af[i] = *(const short8*)&As[r * 32 + pc * 8];
        }
        #pragma unroll
        for (int j = 0; j < 4; ++j) {
            int r = wn + j * 16 + col;
            int pc = quad ^ ((r >> 1) & 3);
            bf[j] = *(const short8*)&Bs[r * 32 + pc * 8];
        }
        #pragma unroll
        for (int i = 0; i < 4; ++i)
            #pragma unroll
            for (int j = 0; j < 4; ++j)
                acc[i][j] = __builtin_amdgcn_mfma_f32_16x16x32_bf16(af[i], bf[j], acc[i][j], 0, 0, 0);
    }

    if (MODE == 0) {
        #pragma unroll
        for (int i = 0; i < 4; ++i)
            #pragma unroll
            for (int j = 0; j < 4; ++j)
                #pragma unroll
                for (int rr = 0; rr < 4; ++rr) {
                    int row = bm + wm + i * 16 + quad * 4 + rr;
                    int cc2 = bn + wn + j * 16 + col;
                    C[(size_t)row * N + cc2] = acc[i][j][rr];
                }
    } else {
        if (bn < QK_N) {
            #pragma unroll
            for (int i = 0; i < 4; ++i)
                #pragma unroll
                for (int j = 0; j < 4; ++j)
                    #pragma unroll
                    for (int rr = 0; rr < 4; ++rr) {
                        int row = bm + wm + i * 16 + quad * 4 + rr;
                        int cc2 = bn + wn + j * 16 + col;
                        qkvb[(size_t)row * QK_N + cc2] = f2bf(acc[i][j][rr]);
                    }
        } else {
            const int kvh = (bn - QK_N) >> 7;
            #pragma unroll
            for (int i = 0; i < 4; ++i)
                #pragma unroll
                for (int j = 0; j < 4; ++j) {
                    int d = wn + j * 16 + col;
                    int tok = bm + wm + i * 16 + quad * 4;
                    ushort4 o;
                    o.x = f2bf(acc[i][j][0]); o.y = f2bf(acc[i][j][1]);
                    o.z = f2bf(acc[i][j][2]); o.w = f2bf(acc[i][j][3]);
                    *(ushort4*)&Vt[((size_t)kvh * HEAD_DIM + d) * T_SEQ + tok] = o;
                }
        }
    }
}

// ---------------------------------------------------------------------------
// Fused RMSNorm + RoPE over bf16 qkvb. q -> Qb (scale folded), k -> Kb.
// ---------------------------------------------------------------------------
__global__ __launch_bounds__(128) void normrope(
    const unsigned short* __restrict__ qkvb, const int* __restrict__ positions,
    const float* __restrict__ qw, const float* __restrict__ kw,
    unsigned short* __restrict__ Qb, unsigned short* __restrict__ Kb)
{
    const int i = blockIdx.x;
    const int h = blockIdx.y;
    const int t = threadIdx.x;
    const unsigned short* ptr;
    const float* w;
    if (h < NUM_HEADS) { ptr = qkvb + (size_t)i * QK_N + h * HEAD_DIM; w = qw; }
    else { ptr = qkvb + (size_t)i * QK_N + Q_SIZE + (h - NUM_HEADS) * HEAD_DIM; w = kw; }

    float x = b2f(ptr[t]);
    float v = x * x;
    #pragma unroll
    for (int off = 32; off; off >>= 1) v += __shfl_xor(v, off, 64);
    __shared__ float sh[2];
    __shared__ float xn[HEAD_DIM];
    if ((t & 63) == 0) sh[t >> 6] = v;
    __syncthreads();
    const float sumsq = sh[0] + sh[1];
    const float inv = rsqrtf(sumsq * (1.0f / HEAD_DIM) + EPS_);
    xn[t] = x * inv * w[t];
    __syncthreads();

    const int d = t & 63;
    const float fr = (float)positions[i] * exp2f(-(float)d * (13.287712379549449f / 64.0f));
    float s, c;
    sincosf(fr, &s, &c);
    const float x1 = xn[d], x2 = xn[d + 64];
    const float val = (t < 64) ? (x1 * c - x2 * s) : (x2 * c + x1 * s);
    if (h < NUM_HEADS)
        Qb[(size_t)i * Q_SIZE + h * HEAD_DIM + t] = f2bf(val * 0.08838834764831845f);
    else
        Kb[((size_t)(h - NUM_HEADS) * T_SEQ + i) * HEAD_DIM + t] = f2bf(val);
}

// ---------------------------------------------------------------------------
// Flash attention: BK=64, split-K over 1024-token chunks, fixed-max softmax,
// ones-column l, heavy-first ordering — unchanged from R5.
// ---------------------------------------------------------------------------
#define BQ 64
#define BK 64

__global__ __launch_bounds__(256) void attn_mfma(
    const unsigned short* __restrict__ Qb, const unsigned short* __restrict__ Kb,
    const unsigned short* __restrict__ Vt, unsigned short* __restrict__ ctxb,
    float* __restrict__ partO, float* __restrict__ partL)
{
    const int h = blockIdx.y;
    int qt, ch;
    {
        int x = blockIdx.x;
        if (x < 16) { qt = 16 + x; ch = 0; }
        else {
            int p = (x - 16) >> 1;
            if (((x - 16) & 1) == 0) { qt = 15 - p; ch = 0; }
            else                     { qt = 31 - p; ch = 1; }
        }
    }
    const int nch = (qt >= 16) ? 2 : 1;
    const int units = (ch == 0) ? ((qt + 1 < 16) ? qt + 1 : 16) : (qt + 1 - 16);
    const int q0 = qt * BQ;
    const int kv = h >> 1;
    const int tid = threadIdx.x;
    const int w = tid >> 6;
    const int lane = tid & 63;
    const int col = lane & 15;
    const int quad = lane >> 4;

    __shared__ unsigned short Ks[2][64 * 128];
    __shared__ unsigned short Vs[2][144 * 64];
    __shared__ unsigned short Ps[4][16][72];

    {
        int x = tid * 4;
        unsigned short vv = (x < 64) ? (unsigned short)0x3F80 : (unsigned short)0;
        ushort4 o = {vv, vv, vv, vv};
        *(ushort4*)&Vs[0][128 * 64 + x] = o;
        *(ushort4*)&Vs[1][128 * 64 + x] = o;
    }

    short8 qf[4];
    {
        const unsigned short* qp = Qb + (size_t)(q0 + w * 16 + col) * Q_SIZE + h * HEAD_DIM;
        #pragma unroll
        for (int c = 0; c < 4; ++c)
            qf[c] = *(const short8*)(qp + c * 32 + quad * 8);
    }

    const unsigned short* kg[4];
    const unsigned short* vg[4];
    #pragma unroll
    for (int it = 0; it < 4; ++it) {
        int s = it * 256 + tid;
        int kr = s >> 4, kp = s & 15, kj = kp ^ (kr & 15);
        kg[it] = Kb + (size_t)kv * T_SEQ * HEAD_DIM + kr * HEAD_DIM + kj * 8;
        int vr = s >> 3, vp = s & 7, vj = vp ^ (vr & 7);
        vg[it] = Vt + (size_t)kv * HEAD_DIM * T_SEQ + (size_t)vr * T_SEQ + vj * 8;
    }

    floatx4 Ob[9];
    #pragma unroll
    for (int cb = 0; cb < 9; ++cb) Ob[cb] = (floatx4){0.f, 0.f, 0.f, 0.f};

    const int wave_qmin = q0 + w * 16;
    const int wave_qmax = wave_qmin + 15;
    const int tok_base = ch * 1024;

    #pragma unroll
    for (int it = 0; it < 4; ++it) {
        stage16(kg[it] + (size_t)tok_base * HEAD_DIM, &Ks[0][(it * 256 + w * 64) * 8]);
        stage16(vg[it] + tok_base, &Vs[0][(it * 256 + w * 64) * 8]);
    }

    for (int u = 0; u < units; ++u) {
        const int t0 = tok_base + u * BK;
        __syncthreads();
        if (u + 1 < units) {
            const int tn = t0 + BK;
            const int b = (u + 1) & 1;
            #pragma unroll
            for (int it = 0; it < 4; ++it) {
                stage16(kg[it] + (size_t)tn * HEAD_DIM, &Ks[b][(it * 256 + w * 64) * 8]);
                stage16(vg[it] + tn, &Vs[b][(it * 256 + w * 64) * 8]);
            }
        }
        if (t0 > wave_qmax) continue;
        const unsigned short* ks = Ks[u & 1];
        const unsigned short* vs = Vs[u & 1];

        floatx4 S[4];
        #pragma unroll
        for (int cb = 0; cb < 4; ++cb) {
            floatx4 a = (floatx4){0.f, 0.f, 0.f, 0.f};
            #pragma unroll
            for (int c = 0; c < 4; ++c) {
                short8 kf = *(const short8*)&ks[((cb * 16 + col) * 16 + ((c * 4 + quad) ^ col)) * 8];
                a = __builtin_amdgcn_mfma_f32_16x16x32_bf16(kf, qf[c], a, 0, 0, 0);
            }
            S[cb] = a;
        }

        const int qr = q0 + w * 16 + col;
        if (t0 + 63 <= wave_qmin) {
            #pragma unroll
            for (int cb = 0; cb < 4; ++cb) {
                ushort4 pk;
                pk.x = f2bf(__expf(S[cb][0])); pk.y = f2bf(__expf(S[cb][1]));
                pk.z = f2bf(__expf(S[cb][2])); pk.w = f2bf(__expf(S[cb][3]));
                *(ushort4*)&Ps[w][col][cb * 16 + quad * 4] = pk;
            }
        } else {
            #pragma unroll
            for (int cb = 0; cb < 4; ++cb) {
                int kt = t0 + cb * 16 + quad * 4;
                ushort4 pk;
                pk.x = (kt + 0 <= qr) ? f2bf(__expf(S[cb][0])) : (unsigned short)0;
                pk.y = (kt + 1 <= qr) ? f2bf(__expf(S[cb][1])) : (unsigned short)0;
                pk.z = (kt + 2 <= qr) ? f2bf(__expf(S[cb][2])) : (unsigned short)0;
                pk.w = (kt + 3 <= qr) ? f2bf(__expf(S[cb][3])) : (unsigned short)0;
                *(ushort4*)&Ps[w][col][cb * 16 + quad * 4] = pk;
            }
        }

        short8 pf[2];
        pf[0] = *(const short8*)&Ps[w][col][quad * 8];
        pf[1] = *(const short8*)&Ps[w][col][32 + quad * 8];
        #pragma unroll
        for (int cb = 0; cb < 9; ++cb) {
            int vrow = cb * 16 + col;
            #pragma unroll
            for (int kk = 0; kk < 2; ++kk) {
                short8 vf = *(const short8*)&vs[(vrow * 8 + ((kk * 4 + quad) ^ (vrow & 7))) * 8];
                Ob[cb] = __builtin_amdgcn_mfma_f32_16x16x32_bf16(pf[kk], vf, Ob[cb], 0, 0, 0);
            }
        }
    }

    if (nch == 1) {
        #pragma unroll
        for (int r = 0; r < 4; ++r) {
            float l = __shfl(Ob[8][r], lane & 48);
            float rl = 1.0f / l;
            const int qrow = q0 + w * 16 + quad * 4 + r;
            #pragma unroll
            for (int cb = 0; cb < 8; ++cb)
                ctxb[(size_t)qrow * Q_SIZE + h * HEAD_DIM + cb * 16 + col] = f2bf(Ob[cb][r] * rl);
        }
    } else {
        const int slot = (h * 16 + (qt - 16)) * 2 + ch;
        float* po = partO + (size_t)slot * (BQ * HEAD_DIM);
        #pragma unroll
        for (int cb = 0; cb < 8; ++cb)
            #pragma unroll
            for (int r = 0; r < 4; ++r)
                po[(w * 16 + quad * 4 + r) * HEAD_DIM + cb * 16 + col] = Ob[cb][r];
        if (col == 0) {
            #pragma unroll
            for (int r = 0; r < 4; ++r)
                partL[slot * BQ + w * 16 + quad * 4 + r] = Ob[8][r];
        }
    }
}

// ---------------------------------------------------------------------------
// Combine: ctx[qt>=16] = (O0 + O1) / (l0 + l1) — unchanged.
// ---------------------------------------------------------------------------
__global__ __launch_bounds__(256) void combine(
    const float* __restrict__ partO, const float* __restrict__ partL,
    unsigned short* __restrict__ ctxb)
{
    const int h = blockIdx.x >> 4;
    const int qi = blockIdx.x & 15;
    const int q0 = (16 + qi) * 64;
    const int slot0 = (h * 16 + qi) * 2;
    const int tid = threadIdx.x;
    const int row = tid >> 2;
    const int seg = tid & 3;

    const float l = partL[slot0 * 64 + row] + partL[(slot0 + 1) * 64 + row];
    const float rl = 1.0f / l;
    const float* p0 = partO + (size_t)slot0 * 8192 + row * 128 + seg * 32;
    const float* p1 = p0 + 8192;
    unsigned short* dst = ctxb + (size_t)(q0 + row) * Q_SIZE + h * HEAD_DIM + seg * 32;
    #pragma unroll
    for (int m = 0; m < 8; ++m) {
        float4 a = *(const float4*)(p0 + m * 4);
        float4 b = *(const float4*)(p1 + m * 4);
        ushort4 o;
        o.x = f2bf((a.x + b.x) * rl); o.y = f2bf((a.y + b.y) * rl);
        o.z = f2bf((a.z + b.z) * rl); o.w = f2bf((a.w + b.w) * rl);
        *(ushort4*)(dst + m * 4) = o;
    }
}

// ---------------------------------------------------------------------------
extern "C" void kernel_launch(void* const* d_in, const int* in_sizes, int n_in,
                              void* d_out, int out_size, void* d_ws, size_t ws_size,
                              hipStream_t stream)
{
    const int*   positions = (const int*)d_in[0];
    const float* hidden    = (const float*)d_in[1];
    const float* qkv_w     = (const float*)d_in[2];
    const float* q_norm_w  = (const float*)d_in[3];
    const float* k_norm_w  = (const float*)d_in[4];
    const float* o_w       = (const float*)d_in[5];
    float* out = (float*)d_out;

    const size_t MB = 1024 * 1024;
    char* ws = (char*)d_ws;
    unsigned short* obf  = (unsigned short*)ws;                 // [0,8)   whole run
    unsigned short* hbf  = (unsigned short*)(ws + 8 * MB);      // [8,16)  dead after QKV GEMM
    unsigned short* wbf  = (unsigned short*)(ws + 16 * MB);     // [16,32) dead after QKV GEMM
    unsigned short* qkvb = (unsigned short*)(ws + 32 * MB);     // [32,44) dead after normrope
    unsigned short* Vt   = (unsigned short*)(ws + 44 * MB);     // [44,48)
    unsigned short* Qb   = (unsigned short*)(ws + 8 * MB);      // [8,16)  over dead hbf
    unsigned short* Kb   = (unsigned short*)(ws + 16 * MB);     // [16,20) over dead wbf
    float* partO         = (float*)(ws + 20 * MB);              // [20,36.8) over dead wbf/qkvb
    float* partL         = (float*)(ws + 37 * MB);              // [37,37.2)
    unsigned short* ctxb = (unsigned short*)(ws + 48 * MB);     // [48,56)

    convert_all<<<(H4 + W4 + O4 + 255) / 256, 256, 0, stream>>>(
        hidden, qkv_w, o_w, hbf, wbf, obf);
    gemm_nt_bf16<1><<<dim3(QKV_N / 128, T_SEQ / 128), 256, 0, stream>>>(
        hbf, wbf, nullptr, qkvb, Vt, T_SEQ, QKV_N, HIDDEN_);
    normrope<<<dim3(T_SEQ, NUM_HEADS + NUM_KV), 128, 0, stream>>>(
        qkvb, positions, q_norm_w, k_norm_w, Qb, Kb);
    attn_mfma<<<dim3(48, NUM_HEADS), 256, 0, stream>>>(Qb, Kb, Vt, ctxb, partO, partL);
    combine<<<256, 256, 0, stream>>>(partO, partL, ctxb);
    gemm_nt_bf16<0><<<dim3(Q_SIZE / 128, T_SEQ / 128), 256, 0, stream>>>(
        ctxb, obf, out, nullptr, nullptr, T_SEQ, Q_SIZE, HIDDEN_);
}